// Round 8
// baseline (1212.240 us; speedup 1.0000x reference)
//
#include <hip/hip_runtime.h>
#include <cstdio>
#include <cstdint>

// PointNet++ SA module, MI355X. Recompute pipeline; layers 2/3 on MFMA (bf16).
// B=16, N=4096, M=1024; scale0: r=0.1,K=32,[67,64,64,128]; scale1: r=0.2,K=64,[67,64,96,128]

constexpr int BATCH = 16, NPTS = 4096, MCTR = 1024;
constexpr int BM = BATCH * MCTR;   // 16384 centers
constexpr int NSLOT = 32;          // stats contention-spreading slots

typedef short bf16x8 __attribute__((ext_vector_type(8)));
typedef float f32x4  __attribute__((ext_vector_type(4)));
typedef float f32x2  __attribute__((ext_vector_type(2)));

__device__ __forceinline__ ushort f2bf(float f) {
  uint32_t u = __float_as_uint(f);
  u += 0x7fffu + ((u >> 16) & 1u);   // RNE
  return (ushort)(u >> 16);
}
__device__ __forceinline__ uint32_t packbf(float a, float b) {
  return (uint32_t)f2bf(a) | ((uint32_t)f2bf(b) << 16);
}
__device__ __forceinline__ unsigned long long umax64(unsigned long long a,
                                                     unsigned long long b) {
  return (a > b) ? a : b;
}

// DPP-based max over u64 keys (old=0 is identity: keys are non-negative).
//  0xB1 xor1, 0x4E xor2, 0x124 row_ror:4, 0x128 row_ror:8 -> row max;
//  0x142 row_bcast15, 0x143 row_bcast31 -> lane 63 = full wave max. [proven]
template <int CTRL>
__device__ __forceinline__ unsigned long long dpp_max(unsigned long long k) {
  int lo = (int)(uint32_t)k, hi = (int)(uint32_t)(k >> 32);
  uint32_t plo = (uint32_t)__builtin_amdgcn_update_dpp(0, lo, CTRL, 0xf, 0xf, false);
  uint32_t phi = (uint32_t)__builtin_amdgcn_update_dpp(0, hi, CTRL, 0xf, 0xf, false);
  unsigned long long pk = ((unsigned long long)phi << 32) | plo;
  return (pk > k) ? pk : k;
}

// ---------------- farthest point sampling (device body, fused kernel) ----------------
// R3-proven structure (612us) + two bit-exact micro-opts (R8):
//  (a) in-thread selection as a u64-key max TREE (precomputed ~idx low words;
//      4 partials + 2-level merge, depth ~6 vs the old 16-deep cndmask chain).
//      Key order == the DPP stage's order => identical winner.
//  (b) candidate-coords overlap: post-barrier, extract all 4 wave-winner
//      indices from the key read and issue all 12 coord loads BEFORE the
//      umax tree; select via cndmask reusing the same compares. Removes the
//      serial lX[far] hop (its latency now overlaps the tree+select).
// Per iter: packed update + key tree -> 6-stage DPP -> 4 keys to LDS
// (double-buffered) -> ONE barrier -> b128 key read -> 12 candidate loads ||
// umax tree -> cndmask coord select. NO global stores in the loop.
// FAILED ALTERNATIVES (do not retry without new evidence):
//  - 1024-thr block + per-lane readback (R1): replay-divergence tripwire.
//  - same-kernel spin-wait ballq consumers (R4): LDS-capped convoy, +554us.
//  - coord-carry through the selection chain + 64b-DPP readback (R5): +250us.
__device__ __forceinline__ void fps_body(int b, int t, const float* __restrict__ pc,
                                         float* __restrict__ newpc_out,
                                         char* __restrict__ smem) {
  float* lX = (float*)smem;
  float* lY = lX + NPTS;
  float* lZ = lY + NPTS;
  int*   sampL = (int*)(smem + 3 * NPTS * 4);                       // 4 KB
  unsigned long long* wkey =
      (unsigned long long*)(smem + 3 * NPTS * 4 + MCTR * 4);        // 2 x 4 keys
  const int lane = t & 63;
  const int w = t >> 6;
  const float* px = pc + (size_t)b * 3 * NPTS;
  f32x2 X2[8], Y2[8], Z2[8], D2[8];
  unsigned lowk[16];
#pragma unroll
  for (int j = 0; j < 16; j++) {
    int p = t + 256 * j;
    float x = px[p], y = px[NPTS + p], z = px[2 * NPTS + p];
    X2[j >> 1][j & 1] = x; Y2[j >> 1][j & 1] = y; Z2[j >> 1][j & 1] = z;
    D2[j >> 1][j & 1] = 1e10f;
    lX[p] = x; lY[p] = y; lZ[p] = z;
    lowk[j] = ~(unsigned)p;     // key low word: ~idx => first-index tie-break
  }
  if (t == 0) sampL[0] = 0;
  __syncthreads();
  float cx = lX[0], cy = lY[0], cz = lZ[0];   // sample 0 = point 0
  for (int it = 1; it < MCTR; it++) {
    unsigned long long kk4[4];
    {
#pragma clang fp contract(off)
      f32x2 cx2 = {cx, cx}, cy2 = {cy, cy}, cz2 = {cz, cz};
#pragma unroll
      for (int j2 = 0; j2 < 8; j2++) {
        f32x2 dx = X2[j2] - cx2, dy = Y2[j2] - cy2, dz = Z2[j2] - cz2;
        f32x2 d = dx * dx + dy * dy + dz * dz;   // ((x^2+y^2)+z^2), no fma
        f32x2 dm;
        dm[0] = fminf(D2[j2][0], d[0]);
        dm[1] = fminf(D2[j2][1], d[1]);
        D2[j2] = dm;
        // d >= 0 => sign clear => uint order == float order; ~idx low word
        // => u64 max == (max value, first index) — matches the old serial '>'
        unsigned long long ka =
            ((unsigned long long)__float_as_uint(dm[0]) << 32) | lowk[2 * j2];
        unsigned long long kb =
            ((unsigned long long)__float_as_uint(dm[1]) << 32) | lowk[2 * j2 + 1];
        unsigned long long kp2 = umax64(ka, kb);
        kk4[j2 & 3] = (j2 < 4) ? kp2 : umax64(kk4[j2 & 3], kp2);
      }
    }
    unsigned long long key = umax64(umax64(kk4[0], kk4[1]), umax64(kk4[2], kk4[3]));
    key = dpp_max<0xB1>(key);    // xor 1
    key = dpp_max<0x4E>(key);    // xor 2
    key = dpp_max<0x124>(key);   // row_ror:4
    key = dpp_max<0x128>(key);   // row_ror:8   -> row max in all 16 lanes
    key = dpp_max<0x142>(key);   // row_bcast15
    key = dpp_max<0x143>(key);   // row_bcast31 -> lane 63 = full wave max
    if (lane == 63) wkey[(it & 1) * 4 + w] = key;
    __syncthreads();
    const ulonglong2* kp = (const ulonglong2*)(wkey + (it & 1) * 4);
    ulonglong2 k0 = kp[0], k1 = kp[1];
    // candidate indices + 12 coord loads issued before/while the tree runs
    int f0 = (int)(~(unsigned)k0.x), f1 = (int)(~(unsigned)k0.y);
    int f2 = (int)(~(unsigned)k1.x), f3 = (int)(~(unsigned)k1.y);
    float x0 = lX[f0], x1 = lX[f1], x2c = lX[f2], x3 = lX[f3];
    float y0 = lY[f0], y1 = lY[f1], y2c = lY[f2], y3 = lY[f3];
    float z0 = lZ[f0], z1 = lZ[f1], z2c = lZ[f2], z3 = lZ[f3];
    bool s01 = k0.x > k0.y;
    bool s23 = k1.x > k1.y;
    unsigned long long m01 = s01 ? k0.x : k0.y;
    unsigned long long m23 = s23 ? k1.x : k1.y;
    bool sf = m01 > m23;
    unsigned long long kk = sf ? m01 : m23;
    float cx01 = s01 ? x0 : x1, cy01 = s01 ? y0 : y1, cz01 = s01 ? z0 : z1;
    float cx23 = s23 ? x2c : x3, cy23 = s23 ? y2c : y3, cz23 = s23 ? z2c : z3;
    cx = sf ? cx01 : cx23;
    cy = sf ? cy01 : cy23;
    cz = sf ? cz01 : cz23;
    if (t == 0) sampL[it] = (int)(~(unsigned)kk);   // off the critical path
  }
  __syncthreads();
  float* npc = newpc_out + (size_t)b * 3 * MCTR;
  for (int m = t; m < MCTR; m += 256) {
    int f = sampL[m];
    npc[m] = lX[f]; npc[MCTR + m] = lY[f]; npc[2 * MCTR + m] = lZ[f];
  }
}

// ---------------- U = bf16(W_feat . feat + b1) (device body, fused kernel) --------
__device__ __forceinline__ void u_body(const float* __restrict__ feat,
                                       const float* __restrict__ W,
                                       const float* __restrict__ bias,
                                       ushort* __restrict__ Ub, int ub,
                                       char* __restrict__ smem) {
  float* wl = (float*)smem;          // wl[c*64+o] = W[o*67+3+c]
  int t = threadIdx.x;
#pragma unroll
  for (int i = 0; i < 16; i++) {
    int r = t + 256 * i;
    wl[r] = W[(r & 63) * 67 + 3 + (r >> 6)];
  }
  __syncthreads();
  int gid = ub * 256 + t;
  int b = gid >> 12, n = gid & 4095;
  float acc[64];
#pragma unroll
  for (int o = 0; o < 64; o++) acc[o] = bias[o];
  const float* fb = feat + (size_t)b * 64 * NPTS + n;
  for (int c = 0; c < 64; c++) {
    float x = fb[(size_t)c * NPTS];
    const f32x4* w4 = (const f32x4*)(wl + c * 64);
#pragma unroll
    for (int q = 0; q < 16; q++) {
      f32x4 wv = w4[q];
      acc[4 * q + 0] = fmaf(wv[0], x, acc[4 * q + 0]);
      acc[4 * q + 1] = fmaf(wv[1], x, acc[4 * q + 1]);
      acc[4 * q + 2] = fmaf(wv[2], x, acc[4 * q + 2]);
      acc[4 * q + 3] = fmaf(wv[3], x, acc[4 * q + 3]);
    }
  }
  uint4* o4 = (uint4*)(Ub + (size_t)gid * 64);
#pragma unroll
  for (int qq = 0; qq < 8; qq++)
    o4[qq] = make_uint4(packbf(acc[8*qq+0], acc[8*qq+1]), packbf(acc[8*qq+2], acc[8*qq+3]),
                        packbf(acc[8*qq+4], acc[8*qq+5]), packbf(acc[8*qq+6], acc[8*qq+7]));
}

// ---------------- fused stage A: FPS (16) | U0 (256) | U1 (256) | prep (154) ------
__global__ __launch_bounds__(256) void fused_stageA(
    const float* __restrict__ pc, const float* __restrict__ feat,
    const float* __restrict__ W00, const float* __restrict__ b00,
    const float* __restrict__ W01, const float* __restrict__ W02,
    const float* __restrict__ W10, const float* __restrict__ b10,
    const float* __restrict__ W11, const float* __restrict__ W12,
    float* __restrict__ newpc_out, ushort* __restrict__ Ub0,
    ushort* __restrict__ Ub1, float* __restrict__ wt, ushort* __restrict__ wf) {
  __shared__ __align__(16) char smem[3 * NPTS * 4 + MCTR * 4 + 64];   // 53312 B
  int bx = blockIdx.x, t = threadIdx.x;
  if (bx < 16) { fps_body(bx, t, pc, newpc_out, smem); return; }
  if (bx < 528) {
    int ub = bx - 16;
    if (ub < 256) u_body(feat, W00, b00, Ub0, ub, smem);
    else          u_body(feat, W10, b10, Ub1, ub - 256, smem);
    return;
  }
  // wt (float): WtF0@0(4096,unused) Wt1x0@4096(192) WtF1@4288(4096,unused) Wt1x1@8384(192)
  // wf (ushort): W2f0@0(4096) W3f0@4096(8192) W2f1@12288(6144) W3f1@18432(12288)
  int e = (bx - 528) * 256 + t;
  if (e < 4096) { wt[e] = W00[(e & 63) * 67 + 3 + (e >> 6)]; return; }
  if (e < 4288) { int r = e - 4096; wt[e] = W00[(r & 63) * 67 + (r >> 6)]; return; }
  if (e < 8384) { int r = e - 4288; wt[e] = W10[(r & 63) * 67 + 3 + (r >> 6)]; return; }
  if (e < 8576) { int r = e - 8384; wt[e] = W10[(r & 63) * 67 + (r >> 6)]; return; }
  int e2 = e - 8576;
  if (e2 >= 30720) return;
  const float* W; int CIN, MT, off;
  if (e2 < 4096)       { W = W01; CIN = 64; MT = 4; off = 0; }
  else if (e2 < 12288) { W = W02; CIN = 64; MT = 8; off = 4096; }
  else if (e2 < 18432) { W = W11; CIN = 64; MT = 6; off = 12288; }
  else                 { W = W12; CIN = 96; MT = 8; off = 18432; }
  int r = e2 - off;
  int j = r & 7, lane = (r >> 3) & 63, fm = r >> 9;
  int kc = fm / MT, mt = fm % MT;
  int out_ch = mt * 16 + (lane & 15);
  int in_ch  = kc * 32 + (lane >> 4) * 8 + j;
  wf[e2] = f2bf(W[out_ch * CIN + in_ch]);
}

// ---------------- ball query: wave per center, ballot-ranked first-K ----------------
template <int K>
__device__ __forceinline__ void ballq_body(int bx, const float* __restrict__ pc,
                                           const float* __restrict__ newpc,
                                           int* __restrict__ gidx, float r2) {
  int lane = threadIdx.x & 63;
  int wave = threadIdx.x >> 6;
  int center = bx * 4 + wave;
  int b = center >> 10, m = center & 1023;
  const float* nb = newpc + (size_t)b * 3 * MCTR + m;
  float cx = nb[0], cy = nb[MCTR], cz = nb[2 * MCTR];
  const float* px = pc + (size_t)b * 3 * NPTS;
  int cnt = 0;
  int firstn = 0x7fffffff;
  for (int chunk = 0; chunk < NPTS / 64 && cnt < K; chunk++) {
    int n = chunk * 64 + lane;
    float dx = __fsub_rn(cx, px[n]);
    float dy = __fsub_rn(cy, px[NPTS + n]);
    float dz = __fsub_rn(cz, px[2 * NPTS + n]);
    float d2 = __fadd_rn(__fadd_rn(__fmul_rn(dx, dx), __fmul_rn(dy, dy)), __fmul_rn(dz, dz));
    bool in = d2 < r2;
    unsigned long long ball = __ballot(in);
    int pos = cnt + (int)__popcll(ball & ((1ull << lane) - 1ull));
    if (in && pos < K) gidx[(size_t)center * K + pos] = n;
    if (in && pos == 0) firstn = n;
    cnt += (int)__popcll(ball);
  }
#pragma unroll
  for (int off = 32; off; off >>= 1) firstn = min(firstn, __shfl_xor(firstn, off));
  if (lane < K && lane >= cnt) gidx[(size_t)center * K + lane] = firstn;
}

__global__ __launch_bounds__(256) void ballq_fused(const float* __restrict__ pc,
                                                   const float* __restrict__ newpc,
                                                   int* __restrict__ gidx0,
                                                   int* __restrict__ gidx1,
                                                   float r2a, float r2b) {
  int bx = blockIdx.x;
  if (bx < BM / 4) ballq_body<32>(bx, pc, newpc, gidx0, r2a);
  else             ballq_body<64>(bx - BM / 4, pc, newpc, gidx1, r2b);
}

// ---------------- bf16 U gather + layer1 (shared by l1 / mfma_pass) ----------------
__device__ __forceinline__ void layer1_compute(const ushort* __restrict__ Ub,
                                               const float* __restrict__ pc,
                                               const float* __restrict__ newpc,
                                               const float* __restrict__ Wt1,
                                               int b, int m, int idx, float* v1) {
  float dx = pc[((size_t)b * 3 + 0) * NPTS + idx] - newpc[((size_t)b * 3 + 0) * MCTR + m];
  float dy = pc[((size_t)b * 3 + 1) * NPTS + idx] - newpc[((size_t)b * 3 + 1) * MCTR + m];
  float dz = pc[((size_t)b * 3 + 2) * NPTS + idx] - newpc[((size_t)b * 3 + 2) * MCTR + m];
  const uint4* u4 = (const uint4*)(Ub + (size_t)((b << 12) + idx) * 64);
#pragma unroll
  for (int qq = 0; qq < 8; qq++) {
    uint4 u = u4[qq];
    v1[8*qq+0] = __uint_as_float(u.x << 16);
    v1[8*qq+1] = __uint_as_float(u.x & 0xffff0000u);
    v1[8*qq+2] = __uint_as_float(u.y << 16);
    v1[8*qq+3] = __uint_as_float(u.y & 0xffff0000u);
    v1[8*qq+4] = __uint_as_float(u.z << 16);
    v1[8*qq+5] = __uint_as_float(u.z & 0xffff0000u);
    v1[8*qq+6] = __uint_as_float(u.w << 16);
    v1[8*qq+7] = __uint_as_float(u.w & 0xffff0000u);
  }
#pragma unroll
  for (int o = 0; o < 64; o++) v1[o] = fmaf(Wt1[o], dx, v1[o]);
#pragma unroll
  for (int o = 0; o < 64; o++) v1[o] = fmaf(Wt1[64 + o], dy, v1[o]);
#pragma unroll
  for (int o = 0; o < 64; o++) v1[o] = fmaf(Wt1[128 + o], dz, v1[o]);
}

// ---------------- layer-1 stats pass (VALU; cheap) ----------------
__device__ __forceinline__ void wave_reduce32(const float* vals, float* tile, int t,
                                              float* swrow, int co) {
  float* myrow = tile + t * 32;
  int rsw = t & 31;
#pragma unroll
  for (int o = 0; o < 32; o++) myrow[o ^ rsw] = vals[o];
  __syncthreads();
  int lane = t & 63;
  int ch = lane & 31, sub = lane >> 5;
  const float* base = tile + (t & ~63) * 32;
  float s = 0.f, s2 = 0.f;
#pragma unroll
  for (int r = 0; r < 32; r++) {
    int row = sub * 32 + r;
    float v = base[row * 32 + (ch ^ (row & 31))];
    s += v; s2 = fmaf(v, v, s2);
  }
  float st = s + __shfl_xor(s, 32);
  float st2 = s2 + __shfl_xor(s2, 32);
  if (sub == 0) {
    swrow[co + ch] += st;
    swrow[128 + co + ch] += st2;
  }
  __syncthreads();
}

template <int K>
__device__ __forceinline__ void l1_body(
    int bx, const ushort* __restrict__ Ub, const float* __restrict__ pc,
    const float* __restrict__ newpc, const int* __restrict__ gidx,
    const float* __restrict__ Wt1, float* __restrict__ stats,
    float* tile, float* sAcc /* [2][256] flat */) {
  const int t = threadIdx.x;
  const int w = t >> 6;
  const int p = bx * 128 + t;
  const int bm = p / K;
  const int b = bm >> 10, m = bm & 1023;
  const int idx = gidx[p];
  for (int i = t; i < 512; i += 128) sAcc[i] = 0.f;

  float v1[64];
  layer1_compute(Ub, pc, newpc, Wt1, b, m, idx, v1);

  wave_reduce32(v1,      tile, t, sAcc + w * 256, 0);
  wave_reduce32(v1 + 32, tile, t, sAcc + w * 256, 32);

  __syncthreads();
  float* dst = stats + (size_t)(bx & (NSLOT - 1)) * 128;
  for (int i = t; i < 64; i += 128) {
    atomicAdd(&dst[i],      sAcc[i]       + sAcc[256 + i]);
    atomicAdd(&dst[64 + i], sAcc[128 + i] + sAcc[256 + 128 + i]);
  }
}

__global__ __launch_bounds__(128, 2) void l1_fused(
    const ushort* __restrict__ Ub0, const ushort* __restrict__ Ub1,
    const float* __restrict__ pc, const float* __restrict__ newpc,
    const int* __restrict__ gidx0, const int* __restrict__ gidx1,
    const float* __restrict__ Wt1a, const float* __restrict__ Wt1b,
    float* __restrict__ st0, float* __restrict__ st1) {
  __shared__ float tile[128 * 32];
  __shared__ float sAccW[2][256];
  constexpr int NB0 = (BM * 32) / 128;
  int bx = blockIdx.x;
  if (bx < NB0) l1_body<32>(bx, Ub0, pc, newpc, gidx0, Wt1a, st0, tile, &sAccW[0][0]);
  else          l1_body<64>(bx - NB0, Ub1, pc, newpc, gidx1, Wt1b, st1, tile, &sAccW[0][0]);
}

// ---------------- MFMA MLP pass: layer1 (VALU) -> layer2[/3] (MFMA) ----------------
// SEPARATE kernel per scale with OWN typed __shared__ arrays. R6 LESSON: fusing
// both scales into one kernel via a char[] LDS blob + reinterpret-casts cost
// +244us — the cast blob defeats LDS alias analysis and serializes the
// ds_read/MFMA overlap. Keep distinct __shared__ declarations.
// NL=2: stats of pre-BN layer2.  NL=3: stats of pre-BN layer3 + per-center
// max/min stored as bf16 (LOSSLESS: maxed values are already bf16-rounded via
// x3s — verified R6).
template <int K, int C2, int NL>
__global__ __launch_bounds__(256, 2) void mfma_pass(
    const ushort* __restrict__ Ub, const float* __restrict__ pc,
    const float* __restrict__ newpc, const int* __restrict__ gidx,
    const float* __restrict__ Wt1,
    const ushort* __restrict__ W2f, const ushort* __restrict__ W3f,
    const float* __restrict__ b2, const float* __restrict__ b3,
    const float* __restrict__ cA1, const float* __restrict__ cC1,
    const float* __restrict__ cA2, const float* __restrict__ cC2,
    float* __restrict__ stats, ushort* __restrict__ maxbuf,
    ushort* __restrict__ minbuf) {
  constexpr int MT2 = C2 / 16, KC3 = C2 / 32;
  constexpr int CLs = (NL == 2) ? C2 : 128;
  constexpr int SSTR = CLs + 4;                       // scratch row stride (ushorts)
  __shared__ __align__(16) ushort x1f[4][2][4][64][8];         // 32 KB, B-frag order
  __shared__ __align__(16) ushort x2f[(NL == 3) ? 4 : 1][KC3][4][16][8];
  __shared__ __align__(16) ushort x3s[4][16][SSTR];            // pre-BN scratch rows
  __shared__ float sAccW[4][256];

  const int t = threadIdx.x, w = t >> 6, lane = t & 63;
  const int q = lane >> 4, n = lane & 15;
  const int p = blockIdx.x * 256 + t;
  const int bm = p / K;
  const int b = bm >> 10, m = bm & 1023;
  const int idx = gidx[p];

  // ---- layer1 per-thread (position = t) ----
  {
    float v1[64];
    layer1_compute(Ub, pc, newpc, Wt1, b, m, idx, v1);
    // bn1relu -> x1f B-frag rows (ch = kc*32 + q*8 + j), own 16B slot per thread
    int nw = t & 63;
#pragma unroll
    for (int g = 0; g < 8; g++) {
      uint32_t d0, d1, d2, d3;
      int c = g * 8;
      d0 = packbf(fmaxf(0.f, fmaf(cA1[c+0], v1[c+0], cC1[c+0])),
                  fmaxf(0.f, fmaf(cA1[c+1], v1[c+1], cC1[c+1])));
      d1 = packbf(fmaxf(0.f, fmaf(cA1[c+2], v1[c+2], cC1[c+2])),
                  fmaxf(0.f, fmaf(cA1[c+3], v1[c+3], cC1[c+3])));
      d2 = packbf(fmaxf(0.f, fmaf(cA1[c+4], v1[c+4], cC1[c+4])),
                  fmaxf(0.f, fmaf(cA1[c+5], v1[c+5], cC1[c+5])));
      d3 = packbf(fmaxf(0.f, fmaf(cA1[c+6], v1[c+6], cC1[c+6])),
                  fmaxf(0.f, fmaf(cA1[c+7], v1[c+7], cC1[c+7])));
      *(uint4*)&x1f[w][g >> 2][g & 3][nw][0] = make_uint4(d0, d1, d2, d3);
    }
  }
  asm volatile("s_waitcnt lgkmcnt(0)" ::: "memory");

  // ---- preload A-fragments into registers ----
  bf16x8 A2[2 * MT2];
#pragma unroll
  for (int i = 0; i < 2 * MT2; i++) A2[i] = *(const bf16x8*)(W2f + (i * 64 + lane) * 8);
  bf16x8 A3[(NL == 3) ? KC3 * 8 : 1];
  if (NL == 3) {
#pragma unroll
    for (int i = 0; i < KC3 * 8; i++) A3[i] = *(const bf16x8*)(W3f + (i * 64 + lane) * 8);
  }

  float sS0 = 0.f, sS1 = 0.f, sS20 = 0.f, sS21 = 0.f;
  float mx0 = -3.4e38f, mx1 = -3.4e38f, mn0 = 3.4e38f, mn1 = 3.4e38f;

#pragma unroll
  for (int tl = 0; tl < 4; tl++) {
    // layer2 MFMA
    bf16x8 bf2[2];
#pragma unroll
    for (int kc = 0; kc < 2; kc++)
      bf2[kc] = *(const bf16x8*)&x1f[w][kc][q][tl * 16 + n][0];
    f32x4 acc2[MT2];
#pragma unroll
    for (int mt = 0; mt < MT2; mt++) acc2[mt] = *(const f32x4*)(b2 + mt * 16 + q * 4);
#pragma unroll
    for (int kc = 0; kc < 2; kc++)
#pragma unroll
      for (int mt = 0; mt < MT2; mt++)
        acc2[mt] = __builtin_amdgcn_mfma_f32_16x16x32_bf16(A2[kc * MT2 + mt], bf2[kc],
                                                           acc2[mt], 0, 0, 0);
    if (NL == 2) {
      // pre-BN layer2 -> scratch
#pragma unroll
      for (int mt = 0; mt < MT2; mt++) {
        int ch0 = mt * 16 + q * 4;
        *(uint2*)&x3s[w][n][ch0] = make_uint2(packbf(acc2[mt][0], acc2[mt][1]),
                                              packbf(acc2[mt][2], acc2[mt][3]));
      }
    } else {
      // bn2relu -> x2f B-frag rows
#pragma unroll
      for (int mt = 0; mt < MT2; mt++) {
        int ch0 = mt * 16 + q * 4;
        f32x4 ca = *(const f32x4*)(cA2 + ch0);
        f32x4 cc = *(const f32x4*)(cC2 + ch0);
        float r0 = fmaxf(0.f, fmaf(ca[0], acc2[mt][0], cc[0]));
        float r1 = fmaxf(0.f, fmaf(ca[1], acc2[mt][1], cc[1]));
        float r2 = fmaxf(0.f, fmaf(ca[2], acc2[mt][2], cc[2]));
        float r3 = fmaxf(0.f, fmaf(ca[3], acc2[mt][3], cc[3]));
        int kc2 = ch0 >> 5, q2 = (ch0 >> 3) & 3, j0 = ch0 & 7;
        *(uint2*)&x2f[w][kc2][q2][n][j0] = make_uint2(packbf(r0, r1), packbf(r2, r3));
      }
      asm volatile("s_waitcnt lgkmcnt(0)" ::: "memory");
      // layer3 MFMA
      f32x4 acc3[8];
#pragma unroll
      for (int mt = 0; mt < 8; mt++) acc3[mt] = *(const f32x4*)(b3 + mt * 16 + q * 4);
#pragma unroll
      for (int kc = 0; kc < KC3; kc++) {
        bf16x8 bf3 = *(const bf16x8*)&x2f[w][kc][q][n][0];
#pragma unroll
        for (int mt = 0; mt < 8; mt++)
          acc3[mt] = __builtin_amdgcn_mfma_f32_16x16x32_bf16(A3[kc * 8 + mt], bf3,
                                                             acc3[mt], 0, 0, 0);
      }
      // pre-BN layer3 -> scratch
#pragma unroll
      for (int mt = 0; mt < 8; mt++) {
        int ch0 = mt * 16 + q * 4;
        *(uint2*)&x3s[w][n][ch0] = make_uint2(packbf(acc3[mt][0], acc3[mt][1]),
                                              packbf(acc3[mt][2], acc3[mt][3]));
      }
    }
    asm volatile("s_waitcnt lgkmcnt(0)" ::: "memory");
    // readback reduce: this lane owns channels (2*lane, 2*lane+1)
    if (2 * lane < CLs) {
#pragma unroll
      for (int pos = 0; pos < 16; pos++) {
        uint32_t u = *(const uint32_t*)&x3s[w][pos][2 * lane];
        float v0 = __uint_as_float(u << 16);
        float v1v = __uint_as_float(u & 0xffff0000u);
        sS0 += v0;  sS20 = fmaf(v0, v0, sS20);
        sS1 += v1v; sS21 = fmaf(v1v, v1v, sS21);
        if (NL == 3) {
          mx0 = fmaxf(mx0, v0);  mn0 = fminf(mn0, v0);
          mx1 = fmaxf(mx1, v1v); mn1 = fminf(mn1, v1v);
        }
      }
    }
    if (NL == 3) {
      bool fl = (K == 64) ? (tl == 3) : ((tl & 1) == 1);
      if (fl) {
        int center = (K == 64) ? (blockIdx.x * 4 + w)
                               : (blockIdx.x * 8 + w * 2 + (tl >> 1));
        // bf16 store (lossless; verified R6)
        *(uint32_t*)&maxbuf[(size_t)center * 128 + 2 * lane] = packbf(mx0, mx1);
        *(uint32_t*)&minbuf[(size_t)center * 128 + 2 * lane] = packbf(mn0, mn1);
        mx0 = mx1 = -3.4e38f; mn0 = mn1 = 3.4e38f;
      }
    }
    asm volatile("s_waitcnt lgkmcnt(0)" ::: "memory");   // scratch reuse next tl
  }

  // ---- stats: per-wave LDS row, then one slotted flush per block ----
  {
    int ch = 2 * lane;
    if (ch < CLs) {
      sAccW[w][ch] = sS0;        sAccW[w][ch + 1] = sS1;
      sAccW[w][CLs + ch] = sS20; sAccW[w][CLs + ch + 1] = sS21;
    }
  }
  __syncthreads();
  float* dst = stats + (size_t)(blockIdx.x & (NSLOT - 1)) * (2 * CLs);
  for (int i = t; i < 2 * CLs; i += 256)
    atomicAdd(&dst[i], sAccW[0][i] + sAccW[1][i] + sAccW[2][i] + sAccW[3][i]);
}

// ---------------- BN coeffs from slotted stats, both scales in one launch ----------------
__global__ void finalize2_kernel(const float* __restrict__ st0, const float* __restrict__ g0,
                                 const float* __restrict__ be0, float invP0,
                                 float* __restrict__ cAo0, float* __restrict__ cCo0, int C0,
                                 const float* __restrict__ st1, const float* __restrict__ g1,
                                 const float* __restrict__ be1, float invP1,
                                 float* __restrict__ cAo1, float* __restrict__ cCo1, int C1) {
  const float* st = blockIdx.x ? st1 : st0;
  const float* g  = blockIdx.x ? g1  : g0;
  const float* be = blockIdx.x ? be1 : be0;
  float invP = blockIdx.x ? invP1 : invP0;
  float* cA = blockIdx.x ? cAo1 : cAo0;
  float* cC = blockIdx.x ? cCo1 : cCo0;
  int C = blockIdx.x ? C1 : C0;
  int t = threadIdx.x;
  if (t < C) {
    float s = 0.f, s2 = 0.f;
    for (int sl = 0; sl < NSLOT; sl++) {
      s  += st[sl * 2 * C + t];
      s2 += st[sl * 2 * C + C + t];
    }
    float mu = s * invP;
    float var = fmaf(s2, invP, -(mu * mu));
    float a = g[t] / sqrtf(var + 1e-5f);
    cA[t] = a;
    cC[t] = fmaf(-a, mu, be[t]);
  }
}

// ---------------- final output: affine(max/min by sign) + relu, transposed write ----------------
// Both scales in one launch; reads the bf16 max/min buffers (expand via <<16).
__global__ __launch_bounds__(256) void outwrite_fused(
    const ushort* __restrict__ mx0buf, const ushort* __restrict__ mn0buf,
    const ushort* __restrict__ mx1buf, const ushort* __restrict__ mn1buf,
    const float* __restrict__ coef, float* __restrict__ out_feat) {
  __shared__ float tile[64 * 130];
  int bx = blockIdx.x;
  const ushort* mxb; const ushort* mnb; const float* cA3; const float* cC3;
  int chOff, c0;
  if (bx < BM / 64) {
    mxb = mx0buf; mnb = mn0buf; cA3 = coef + 512; cC3 = coef + 640;
    chOff = 0; c0 = bx * 64;
  } else {
    mxb = mx1buf; mnb = mn1buf; cA3 = coef + 768 + 512; cC3 = coef + 768 + 640;
    chOff = 128; c0 = (bx - BM / 64) * 64;
  }
  int t = threadIdx.x;
#pragma unroll
  for (int i = 0; i < 32; i++) {
    int e = i * 256 + t;
    int lc = e >> 7, o = e & 127;
    float a = cA3[o];
    float mv = __uint_as_float(((uint32_t)mxb[(size_t)(c0 + lc) * 128 + o]) << 16);
    float nv = __uint_as_float(((uint32_t)mnb[(size_t)(c0 + lc) * 128 + o]) << 16);
    float v = (a >= 0.f) ? fmaf(a, mv, cC3[o]) : fmaf(a, nv, cC3[o]);
    tile[lc * 130 + o] = fmaxf(v, 0.f);
  }
  __syncthreads();
  int b = c0 >> 10, m0 = c0 & 1023;
#pragma unroll
  for (int j = 0; j < 32; j++) {
    int e = j * 256 + t;
    int lm = e & 63, o = e >> 6;
    out_feat[((size_t)(b * 256 + chOff + o)) * MCTR + m0 + lm] = tile[lm * 130 + o];
  }
}

// ======================= host launch =======================
extern "C" void kernel_launch(void* const* d_in, const int* in_sizes, int n_in,
                              void* d_out, int out_size, void* d_ws, size_t ws_size,
                              hipStream_t stream) {
  (void)in_sizes; (void)n_in; (void)out_size;
  const float* pc   = (const float*)d_in[0];
  const float* feat = (const float*)d_in[1];
  const float *Wp[2][3], *bp[2][3], *gp[2][3], *bep[2][3];
  for (int s = 0; s < 2; s++)
    for (int l = 0; l < 3; l++) {
      int base = 2 + (s * 3 + l) * 4;
      Wp[s][l]  = (const float*)d_in[base + 0];
      bp[s][l]  = (const float*)d_in[base + 1];
      gp[s][l]  = (const float*)d_in[base + 2];
      bep[s][l] = (const float*)d_in[base + 3];
    }

  char* ws = (char*)d_ws;
  float*  statsR  = (float*) (ws + 0x10000);     // 6 x NSLOT x 256 f32 = 192 KB
  float*  coef    = (float*) (ws + 0x40000);     // 2 scales x 768 f32
  float*  wt      = (float*) (ws + 0x42000);     // 8576 f32
  ushort* wf      = (ushort*)(ws + 0x50000);     // 60 KB bf16 A-frags
  ushort* Ub0     = (ushort*)(ws + 0x100000);    // 8 MB [b][n][64] bf16
  ushort* Ub1     = (ushort*)(ws + 0x900000);    // 8 MB
  int*    gidx0   = (int*)   (ws + 0x1100000);   // 2 MB
  int*    gidx1   = (int*)   (ws + 0x1300000);   // 4 MB
  ushort* mxb0    = (ushort*)(ws + 0x1700000);   // 4 MB bf16 [center][128]
  ushort* mnb0    = (ushort*)(ws + 0x1B00000);   // 4 MB
  ushort* mxb1    = (ushort*)(ws + 0x1F00000);   // 4 MB
  ushort* mnb1    = (ushort*)(ws + 0x2300000);   // 4 MB
  const unsigned long long WS_NEEDED = 0x2700000ULL;   // ~39.3 MB
  if (ws_size < WS_NEEDED) {
    fprintf(stderr, "[kernel] ws too small: %zu < %llu\n", ws_size, WS_NEEDED);
    return;
  }
  float* cf0 = coef, *cf1 = coef + 768;
  // per scale: cA1@0 cC1@128 cA2@256 cC2@384 cA3@512 cC3@640

  float* out_newpc = (float*)d_out;
  float* out_feat  = (float*)d_out + (size_t)BATCH * 3 * MCTR;

  const int P0 = BM * 32, P1 = BM * 64;
  const int LSTRIDE = NSLOT * 256;
  float* st10 = statsR + 0 * LSTRIDE, *st20 = statsR + 1 * LSTRIDE, *st30 = statsR + 2 * LSTRIDE;
  float* st11 = statsR + 3 * LSTRIDE, *st21 = statsR + 4 * LSTRIDE, *st31 = statsR + 5 * LSTRIDE;

  hipMemsetAsync(statsR, 0, 6 * NSLOT * 256 * sizeof(float), stream);
  // fused: FPS (blocks 0-15) || U0 (16-271) || U1 (272-527) || prep (528-681)
  fused_stageA<<<682, 256, 0, stream>>>(pc, feat,
                                        Wp[0][0], bp[0][0], Wp[0][1], Wp[0][2],
                                        Wp[1][0], bp[1][0], Wp[1][1], Wp[1][2],
                                        out_newpc, Ub0, Ub1, wt, wf);
  ballq_fused<<<BM / 2, 256, 0, stream>>>(pc, out_newpc, gidx0, gidx1,
                                          (float)(0.1 * 0.1), (float)(0.2 * 0.2));

  l1_fused<<<P0 / 128 + P1 / 128, 128, 0, stream>>>(Ub0, Ub1, pc, out_newpc,
                                                    gidx0, gidx1,
                                                    wt + 4096, wt + 8384, st10, st11);
  finalize2_kernel<<<2, 128, 0, stream>>>(st10, gp[0][0], bep[0][0], 1.0f / P0,
                                          cf0 + 0, cf0 + 128, 64,
                                          st11, gp[1][0], bep[1][0], 1.0f / P1,
                                          cf1 + 0, cf1 + 128, 64);

  mfma_pass<32, 64, 2><<<P0 / 256, 256, 0, stream>>>(Ub0, pc, out_newpc, gidx0,
      wt + 4096, wf + 0, wf + 4096, bp[0][1], bp[0][2],
      cf0 + 0, cf0 + 128, nullptr, nullptr, st20, nullptr, nullptr);
  mfma_pass<64, 96, 2><<<P1 / 256, 256, 0, stream>>>(Ub1, pc, out_newpc, gidx1,
      wt + 8384, wf + 12288, wf + 18432, bp[1][1], bp[1][2],
      cf1 + 0, cf1 + 128, nullptr, nullptr, st21, nullptr, nullptr);
  finalize2_kernel<<<2, 128, 0, stream>>>(st20, gp[0][1], bep[0][1], 1.0f / P0,
                                          cf0 + 256, cf0 + 384, 64,
                                          st21, gp[1][1], bep[1][1], 1.0f / P1,
                                          cf1 + 256, cf1 + 384, 96);

  mfma_pass<32, 64, 3><<<P0 / 256, 256, 0, stream>>>(Ub0, pc, out_newpc, gidx0,
      wt + 4096, wf + 0, wf + 4096, bp[0][1], bp[0][2],
      cf0 + 0, cf0 + 128, cf0 + 256, cf0 + 384, st30, mxb0, mnb0);
  mfma_pass<64, 96, 3><<<P1 / 256, 256, 0, stream>>>(Ub1, pc, out_newpc, gidx1,
      wt + 8384, wf + 12288, wf + 18432, bp[1][1], bp[1][2],
      cf1 + 0, cf1 + 128, cf1 + 256, cf1 + 384, st31, mxb1, mnb1);
  finalize2_kernel<<<2, 128, 0, stream>>>(st30, gp[0][2], bep[0][2], 1.0f / P0,
                                          cf0 + 512, cf0 + 640, 128,
                                          st31, gp[1][2], bep[1][2], 1.0f / P1,
                                          cf1 + 512, cf1 + 640, 128);
  // both output writes in one launch
  outwrite_fused<<<2 * (BM / 64), 256, 0, stream>>>(mxb0, mnb0, mxb1, mnb1,
                                                    coef, out_feat);
}

// Round 9
// 1186.217 us; speedup vs baseline: 1.0219x; 1.0219x over previous
//
#include <hip/hip_runtime.h>
#include <cstdio>
#include <cstdint>

// PointNet++ SA module, MI355X. Recompute pipeline; layers 2/3 on MFMA (bf16).
// B=16, N=4096, M=1024; scale0: r=0.1,K=32,[67,64,64,128]; scale1: r=0.2,K=64,[67,64,96,128]
// BEST MEASURED: R7 configuration, 1191.5us (this file is the exact R7 restore).

constexpr int BATCH = 16, NPTS = 4096, MCTR = 1024;
constexpr int BM = BATCH * MCTR;   // 16384 centers
constexpr int NSLOT = 32;          // stats contention-spreading slots

typedef short bf16x8 __attribute__((ext_vector_type(8)));
typedef float f32x4  __attribute__((ext_vector_type(4)));
typedef float f32x2  __attribute__((ext_vector_type(2)));

__device__ __forceinline__ ushort f2bf(float f) {
  uint32_t u = __float_as_uint(f);
  u += 0x7fffu + ((u >> 16) & 1u);   // RNE
  return (ushort)(u >> 16);
}
__device__ __forceinline__ uint32_t packbf(float a, float b) {
  return (uint32_t)f2bf(a) | ((uint32_t)f2bf(b) << 16);
}
__device__ __forceinline__ unsigned long long umax64(unsigned long long a,
                                                     unsigned long long b) {
  return (a > b) ? a : b;
}

// DPP-based max over u64 keys (old=0 is identity: keys are non-negative).
//  0xB1 xor1, 0x4E xor2, 0x124 row_ror:4, 0x128 row_ror:8 -> row max;
//  0x142 row_bcast15, 0x143 row_bcast31 -> lane 63 = full wave max. [proven]
template <int CTRL>
__device__ __forceinline__ unsigned long long dpp_max(unsigned long long k) {
  int lo = (int)(uint32_t)k, hi = (int)(uint32_t)(k >> 32);
  uint32_t plo = (uint32_t)__builtin_amdgcn_update_dpp(0, lo, CTRL, 0xf, 0xf, false);
  uint32_t phi = (uint32_t)__builtin_amdgcn_update_dpp(0, hi, CTRL, 0xf, 0xf, false);
  unsigned long long pk = ((unsigned long long)phi << 32) | plo;
  return (pk > k) ? pk : k;
}

// ---------------- farthest point sampling (device body, fused kernel) ----------------
// PROVEN version (R3/R7, 612-615us inside stageA). 256-thread block per batch,
// 16 pts/thread as float2 pairs (packed math; contract(off) keeps mul/add
// order bit-exact vs ref). Per iter: centroid LDS fetch -> 8x2-pt packed
// update (serial f32 select chain) -> 6-stage DPP wave reduce (lane63 = wave
// max) -> 4 keys to LDS (double-buffered) -> ONE barrier -> 2x b128 readback
// + umax64 tree. NO global stores in the loop. newpc written once at the end.
// FAILED ALTERNATIVES (do not retry without new evidence) — this body is the
// empirical local optimum after 5 attempts:
//  - 1024-thr block + per-lane readback (R1): replay-divergence tripwire.
//  - same-kernel spin-wait ballq consumers (R4): LDS-capped convoy, +554us.
//  - coord-carry through the selection chain + 64b-DPP readback (R5): +250us.
//  - u64-key selection tree + candidate-coords overlap (R8): +15us (key
//    construction + 64b compares cost more VALU issue than the hidden hop;
//    12 vs 3 in-loop LDS loads). Issue count matters as much as dep depth.
__device__ __forceinline__ void fps_body(int b, int t, const float* __restrict__ pc,
                                         float* __restrict__ newpc_out,
                                         char* __restrict__ smem) {
  float* lX = (float*)smem;
  float* lY = lX + NPTS;
  float* lZ = lY + NPTS;
  int*   sampL = (int*)(smem + 3 * NPTS * 4);                       // 4 KB
  unsigned long long* wkey =
      (unsigned long long*)(smem + 3 * NPTS * 4 + MCTR * 4);        // 2 x 4 keys
  const int lane = t & 63;
  const int w = t >> 6;
  const float* px = pc + (size_t)b * 3 * NPTS;
  f32x2 X2[8], Y2[8], Z2[8], D2[8];
#pragma unroll
  for (int j = 0; j < 16; j++) {
    int p = t + 256 * j;
    float x = px[p], y = px[NPTS + p], z = px[2 * NPTS + p];
    X2[j >> 1][j & 1] = x; Y2[j >> 1][j & 1] = y; Z2[j >> 1][j & 1] = z;
    D2[j >> 1][j & 1] = 1e10f;
    lX[p] = x; lY[p] = y; lZ[p] = z;
  }
  if (t == 0) sampL[0] = 0;
  __syncthreads();
  int far = 0;
  for (int it = 1; it < MCTR; it++) {
    float cx = lX[far], cy = lY[far], cz = lZ[far];
    float bv = -1.0f; int bi = 0;
    {
#pragma clang fp contract(off)
      f32x2 cx2 = {cx, cx}, cy2 = {cy, cy}, cz2 = {cz, cz};
#pragma unroll
      for (int j2 = 0; j2 < 8; j2++) {
        f32x2 dx = X2[j2] - cx2, dy = Y2[j2] - cy2, dz = Z2[j2] - cz2;
        f32x2 d = dx * dx + dy * dy + dz * dz;   // ((x^2+y^2)+z^2), no fma
        f32x2 dm;
        dm[0] = fminf(D2[j2][0], d[0]);
        dm[1] = fminf(D2[j2][1], d[1]);
        D2[j2] = dm;
        // ascending point order => strict '>' keeps first index within thread
        bool g0 = dm[0] > bv;
        bv = g0 ? dm[0] : bv; bi = g0 ? t + 256 * (2 * j2) : bi;
        bool g1 = dm[1] > bv;
        bv = g1 ? dm[1] : bv; bi = g1 ? t + 256 * (2 * j2 + 1) : bi;
      }
    }
    // d >= 0 => sign clear => uint order == float order; ~idx => first-index ties
    unsigned long long key =
        ((unsigned long long)__float_as_uint(bv) << 32) | (unsigned)(~bi);
    key = dpp_max<0xB1>(key);    // xor 1
    key = dpp_max<0x4E>(key);    // xor 2
    key = dpp_max<0x124>(key);   // row_ror:4
    key = dpp_max<0x128>(key);   // row_ror:8   -> row max in all 16 lanes
    key = dpp_max<0x142>(key);   // row_bcast15
    key = dpp_max<0x143>(key);   // row_bcast31 -> lane 63 = full wave max
    if (lane == 63) wkey[(it & 1) * 4 + w] = key;
    __syncthreads();
    const ulonglong2* kp = (const ulonglong2*)(wkey + (it & 1) * 4);
    ulonglong2 k0 = kp[0], k1 = kp[1];
    unsigned long long kk = umax64(umax64(k0.x, k0.y), umax64(k1.x, k1.y));
    far = (int)(~(unsigned)kk);
    if (t == 0) sampL[it] = far;
  }
  __syncthreads();
  float* npc = newpc_out + (size_t)b * 3 * MCTR;
  for (int m = t; m < MCTR; m += 256) {
    int f = sampL[m];
    npc[m] = lX[f]; npc[MCTR + m] = lY[f]; npc[2 * MCTR + m] = lZ[f];
  }
}

// ---------------- U = bf16(W_feat . feat + b1) (device body, fused kernel) --------
__device__ __forceinline__ void u_body(const float* __restrict__ feat,
                                       const float* __restrict__ W,
                                       const float* __restrict__ bias,
                                       ushort* __restrict__ Ub, int ub,
                                       char* __restrict__ smem) {
  float* wl = (float*)smem;          // wl[c*64+o] = W[o*67+3+c]
  int t = threadIdx.x;
#pragma unroll
  for (int i = 0; i < 16; i++) {
    int r = t + 256 * i;
    wl[r] = W[(r & 63) * 67 + 3 + (r >> 6)];
  }
  __syncthreads();
  int gid = ub * 256 + t;
  int b = gid >> 12, n = gid & 4095;
  float acc[64];
#pragma unroll
  for (int o = 0; o < 64; o++) acc[o] = bias[o];
  const float* fb = feat + (size_t)b * 64 * NPTS + n;
  for (int c = 0; c < 64; c++) {
    float x = fb[(size_t)c * NPTS];
    const f32x4* w4 = (const f32x4*)(wl + c * 64);
#pragma unroll
    for (int q = 0; q < 16; q++) {
      f32x4 wv = w4[q];
      acc[4 * q + 0] = fmaf(wv[0], x, acc[4 * q + 0]);
      acc[4 * q + 1] = fmaf(wv[1], x, acc[4 * q + 1]);
      acc[4 * q + 2] = fmaf(wv[2], x, acc[4 * q + 2]);
      acc[4 * q + 3] = fmaf(wv[3], x, acc[4 * q + 3]);
    }
  }
  uint4* o4 = (uint4*)(Ub + (size_t)gid * 64);
#pragma unroll
  for (int qq = 0; qq < 8; qq++)
    o4[qq] = make_uint4(packbf(acc[8*qq+0], acc[8*qq+1]), packbf(acc[8*qq+2], acc[8*qq+3]),
                        packbf(acc[8*qq+4], acc[8*qq+5]), packbf(acc[8*qq+6], acc[8*qq+7]));
}

// ---------------- fused stage A: FPS (16) | U0 (256) | U1 (256) | prep (154) ------
__global__ __launch_bounds__(256) void fused_stageA(
    const float* __restrict__ pc, const float* __restrict__ feat,
    const float* __restrict__ W00, const float* __restrict__ b00,
    const float* __restrict__ W01, const float* __restrict__ W02,
    const float* __restrict__ W10, const float* __restrict__ b10,
    const float* __restrict__ W11, const float* __restrict__ W12,
    float* __restrict__ newpc_out, ushort* __restrict__ Ub0,
    ushort* __restrict__ Ub1, float* __restrict__ wt, ushort* __restrict__ wf) {
  __shared__ __align__(16) char smem[3 * NPTS * 4 + MCTR * 4 + 64];   // 53312 B
  int bx = blockIdx.x, t = threadIdx.x;
  if (bx < 16) { fps_body(bx, t, pc, newpc_out, smem); return; }
  if (bx < 528) {
    int ub = bx - 16;
    if (ub < 256) u_body(feat, W00, b00, Ub0, ub, smem);
    else          u_body(feat, W10, b10, Ub1, ub - 256, smem);
    return;
  }
  // wt (float): WtF0@0(4096,unused) Wt1x0@4096(192) WtF1@4288(4096,unused) Wt1x1@8384(192)
  // wf (ushort): W2f0@0(4096) W3f0@4096(8192) W2f1@12288(6144) W3f1@18432(12288)
  int e = (bx - 528) * 256 + t;
  if (e < 4096) { wt[e] = W00[(e & 63) * 67 + 3 + (e >> 6)]; return; }
  if (e < 4288) { int r = e - 4096; wt[e] = W00[(r & 63) * 67 + (r >> 6)]; return; }
  if (e < 8384) { int r = e - 4288; wt[e] = W10[(r & 63) * 67 + 3 + (r >> 6)]; return; }
  if (e < 8576) { int r = e - 8384; wt[e] = W10[(r & 63) * 67 + (r >> 6)]; return; }
  int e2 = e - 8576;
  if (e2 >= 30720) return;
  const float* W; int CIN, MT, off;
  if (e2 < 4096)       { W = W01; CIN = 64; MT = 4; off = 0; }
  else if (e2 < 12288) { W = W02; CIN = 64; MT = 8; off = 4096; }
  else if (e2 < 18432) { W = W11; CIN = 64; MT = 6; off = 12288; }
  else                 { W = W12; CIN = 96; MT = 8; off = 18432; }
  int r = e2 - off;
  int j = r & 7, lane = (r >> 3) & 63, fm = r >> 9;
  int kc = fm / MT, mt = fm % MT;
  int out_ch = mt * 16 + (lane & 15);
  int in_ch  = kc * 32 + (lane >> 4) * 8 + j;
  wf[e2] = f2bf(W[out_ch * CIN + in_ch]);
}

// ---------------- ball query: wave per center, ballot-ranked first-K ----------------
template <int K>
__device__ __forceinline__ void ballq_body(int bx, const float* __restrict__ pc,
                                           const float* __restrict__ newpc,
                                           int* __restrict__ gidx, float r2) {
  int lane = threadIdx.x & 63;
  int wave = threadIdx.x >> 6;
  int center = bx * 4 + wave;
  int b = center >> 10, m = center & 1023;
  const float* nb = newpc + (size_t)b * 3 * MCTR + m;
  float cx = nb[0], cy = nb[MCTR], cz = nb[2 * MCTR];
  const float* px = pc + (size_t)b * 3 * NPTS;
  int cnt = 0;
  int firstn = 0x7fffffff;
  for (int chunk = 0; chunk < NPTS / 64 && cnt < K; chunk++) {
    int n = chunk * 64 + lane;
    float dx = __fsub_rn(cx, px[n]);
    float dy = __fsub_rn(cy, px[NPTS + n]);
    float dz = __fsub_rn(cz, px[2 * NPTS + n]);
    float d2 = __fadd_rn(__fadd_rn(__fmul_rn(dx, dx), __fmul_rn(dy, dy)), __fmul_rn(dz, dz));
    bool in = d2 < r2;
    unsigned long long ball = __ballot(in);
    int pos = cnt + (int)__popcll(ball & ((1ull << lane) - 1ull));
    if (in && pos < K) gidx[(size_t)center * K + pos] = n;
    if (in && pos == 0) firstn = n;
    cnt += (int)__popcll(ball);
  }
#pragma unroll
  for (int off = 32; off; off >>= 1) firstn = min(firstn, __shfl_xor(firstn, off));
  if (lane < K && lane >= cnt) gidx[(size_t)center * K + lane] = firstn;
}

__global__ __launch_bounds__(256) void ballq_fused(const float* __restrict__ pc,
                                                   const float* __restrict__ newpc,
                                                   int* __restrict__ gidx0,
                                                   int* __restrict__ gidx1,
                                                   float r2a, float r2b) {
  int bx = blockIdx.x;
  if (bx < BM / 4) ballq_body<32>(bx, pc, newpc, gidx0, r2a);
  else             ballq_body<64>(bx - BM / 4, pc, newpc, gidx1, r2b);
}

// ---------------- bf16 U gather + layer1 (shared by l1 / mfma_pass) ----------------
__device__ __forceinline__ void layer1_compute(const ushort* __restrict__ Ub,
                                               const float* __restrict__ pc,
                                               const float* __restrict__ newpc,
                                               const float* __restrict__ Wt1,
                                               int b, int m, int idx, float* v1) {
  float dx = pc[((size_t)b * 3 + 0) * NPTS + idx] - newpc[((size_t)b * 3 + 0) * MCTR + m];
  float dy = pc[((size_t)b * 3 + 1) * NPTS + idx] - newpc[((size_t)b * 3 + 1) * MCTR + m];
  float dz = pc[((size_t)b * 3 + 2) * NPTS + idx] - newpc[((size_t)b * 3 + 2) * MCTR + m];
  const uint4* u4 = (const uint4*)(Ub + (size_t)((b << 12) + idx) * 64);
#pragma unroll
  for (int qq = 0; qq < 8; qq++) {
    uint4 u = u4[qq];
    v1[8*qq+0] = __uint_as_float(u.x << 16);
    v1[8*qq+1] = __uint_as_float(u.x & 0xffff0000u);
    v1[8*qq+2] = __uint_as_float(u.y << 16);
    v1[8*qq+3] = __uint_as_float(u.y & 0xffff0000u);
    v1[8*qq+4] = __uint_as_float(u.z << 16);
    v1[8*qq+5] = __uint_as_float(u.z & 0xffff0000u);
    v1[8*qq+6] = __uint_as_float(u.w << 16);
    v1[8*qq+7] = __uint_as_float(u.w & 0xffff0000u);
  }
#pragma unroll
  for (int o = 0; o < 64; o++) v1[o] = fmaf(Wt1[o], dx, v1[o]);
#pragma unroll
  for (int o = 0; o < 64; o++) v1[o] = fmaf(Wt1[64 + o], dy, v1[o]);
#pragma unroll
  for (int o = 0; o < 64; o++) v1[o] = fmaf(Wt1[128 + o], dz, v1[o]);
}

// ---------------- layer-1 stats pass (VALU; cheap) ----------------
__device__ __forceinline__ void wave_reduce32(const float* vals, float* tile, int t,
                                              float* swrow, int co) {
  float* myrow = tile + t * 32;
  int rsw = t & 31;
#pragma unroll
  for (int o = 0; o < 32; o++) myrow[o ^ rsw] = vals[o];
  __syncthreads();
  int lane = t & 63;
  int ch = lane & 31, sub = lane >> 5;
  const float* base = tile + (t & ~63) * 32;
  float s = 0.f, s2 = 0.f;
#pragma unroll
  for (int r = 0; r < 32; r++) {
    int row = sub * 32 + r;
    float v = base[row * 32 + (ch ^ (row & 31))];
    s += v; s2 = fmaf(v, v, s2);
  }
  float st = s + __shfl_xor(s, 32);
  float st2 = s2 + __shfl_xor(s2, 32);
  if (sub == 0) {
    swrow[co + ch] += st;
    swrow[128 + co + ch] += st2;
  }
  __syncthreads();
}

template <int K>
__device__ __forceinline__ void l1_body(
    int bx, const ushort* __restrict__ Ub, const float* __restrict__ pc,
    const float* __restrict__ newpc, const int* __restrict__ gidx,
    const float* __restrict__ Wt1, float* __restrict__ stats,
    float* tile, float* sAcc /* [2][256] flat */) {
  const int t = threadIdx.x;
  const int w = t >> 6;
  const int p = bx * 128 + t;
  const int bm = p / K;
  const int b = bm >> 10, m = bm & 1023;
  const int idx = gidx[p];
  for (int i = t; i < 512; i += 128) sAcc[i] = 0.f;

  float v1[64];
  layer1_compute(Ub, pc, newpc, Wt1, b, m, idx, v1);

  wave_reduce32(v1,      tile, t, sAcc + w * 256, 0);
  wave_reduce32(v1 + 32, tile, t, sAcc + w * 256, 32);

  __syncthreads();
  float* dst = stats + (size_t)(bx & (NSLOT - 1)) * 128;
  for (int i = t; i < 64; i += 128) {
    atomicAdd(&dst[i],      sAcc[i]       + sAcc[256 + i]);
    atomicAdd(&dst[64 + i], sAcc[128 + i] + sAcc[256 + 128 + i]);
  }
}

__global__ __launch_bounds__(128, 2) void l1_fused(
    const ushort* __restrict__ Ub0, const ushort* __restrict__ Ub1,
    const float* __restrict__ pc, const float* __restrict__ newpc,
    const int* __restrict__ gidx0, const int* __restrict__ gidx1,
    const float* __restrict__ Wt1a, const float* __restrict__ Wt1b,
    float* __restrict__ st0, float* __restrict__ st1) {
  __shared__ float tile[128 * 32];
  __shared__ float sAccW[2][256];
  constexpr int NB0 = (BM * 32) / 128;
  int bx = blockIdx.x;
  if (bx < NB0) l1_body<32>(bx, Ub0, pc, newpc, gidx0, Wt1a, st0, tile, &sAccW[0][0]);
  else          l1_body<64>(bx - NB0, Ub1, pc, newpc, gidx1, Wt1b, st1, tile, &sAccW[0][0]);
}

// ---------------- MFMA MLP pass: layer1 (VALU) -> layer2[/3] (MFMA) ----------------
// SEPARATE kernel per scale with OWN typed __shared__ arrays. R6 LESSON: fusing
// both scales into one kernel via a char[] LDS blob + reinterpret-casts cost
// +244us — the cast blob defeats LDS alias analysis and serializes the
// ds_read/MFMA overlap. Keep distinct __shared__ declarations.
// NL=2: stats of pre-BN layer2.  NL=3: stats of pre-BN layer3 + per-center
// max/min stored as bf16 (LOSSLESS: maxed values are already bf16-rounded via
// x3s — verified R6).
template <int K, int C2, int NL>
__global__ __launch_bounds__(256, 2) void mfma_pass(
    const ushort* __restrict__ Ub, const float* __restrict__ pc,
    const float* __restrict__ newpc, const int* __restrict__ gidx,
    const float* __restrict__ Wt1,
    const ushort* __restrict__ W2f, const ushort* __restrict__ W3f,
    const float* __restrict__ b2, const float* __restrict__ b3,
    const float* __restrict__ cA1, const float* __restrict__ cC1,
    const float* __restrict__ cA2, const float* __restrict__ cC2,
    float* __restrict__ stats, ushort* __restrict__ maxbuf,
    ushort* __restrict__ minbuf) {
  constexpr int MT2 = C2 / 16, KC3 = C2 / 32;
  constexpr int CLs = (NL == 2) ? C2 : 128;
  constexpr int SSTR = CLs + 4;                       // scratch row stride (ushorts)
  __shared__ __align__(16) ushort x1f[4][2][4][64][8];         // 32 KB, B-frag order
  __shared__ __align__(16) ushort x2f[(NL == 3) ? 4 : 1][KC3][4][16][8];
  __shared__ __align__(16) ushort x3s[4][16][SSTR];            // pre-BN scratch rows
  __shared__ float sAccW[4][256];

  const int t = threadIdx.x, w = t >> 6, lane = t & 63;
  const int q = lane >> 4, n = lane & 15;
  const int p = blockIdx.x * 256 + t;
  const int bm = p / K;
  const int b = bm >> 10, m = bm & 1023;
  const int idx = gidx[p];

  // ---- layer1 per-thread (position = t) ----
  {
    float v1[64];
    layer1_compute(Ub, pc, newpc, Wt1, b, m, idx, v1);
    // bn1relu -> x1f B-frag rows (ch = kc*32 + q*8 + j), own 16B slot per thread
    int nw = t & 63;
#pragma unroll
    for (int g = 0; g < 8; g++) {
      uint32_t d0, d1, d2, d3;
      int c = g * 8;
      d0 = packbf(fmaxf(0.f, fmaf(cA1[c+0], v1[c+0], cC1[c+0])),
                  fmaxf(0.f, fmaf(cA1[c+1], v1[c+1], cC1[c+1])));
      d1 = packbf(fmaxf(0.f, fmaf(cA1[c+2], v1[c+2], cC1[c+2])),
                  fmaxf(0.f, fmaf(cA1[c+3], v1[c+3], cC1[c+3])));
      d2 = packbf(fmaxf(0.f, fmaf(cA1[c+4], v1[c+4], cC1[c+4])),
                  fmaxf(0.f, fmaf(cA1[c+5], v1[c+5], cC1[c+5])));
      d3 = packbf(fmaxf(0.f, fmaf(cA1[c+6], v1[c+6], cC1[c+6])),
                  fmaxf(0.f, fmaf(cA1[c+7], v1[c+7], cC1[c+7])));
      *(uint4*)&x1f[w][g >> 2][g & 3][nw][0] = make_uint4(d0, d1, d2, d3);
    }
  }
  asm volatile("s_waitcnt lgkmcnt(0)" ::: "memory");

  // ---- preload A-fragments into registers ----
  bf16x8 A2[2 * MT2];
#pragma unroll
  for (int i = 0; i < 2 * MT2; i++) A2[i] = *(const bf16x8*)(W2f + (i * 64 + lane) * 8);
  bf16x8 A3[(NL == 3) ? KC3 * 8 : 1];
  if (NL == 3) {
#pragma unroll
    for (int i = 0; i < KC3 * 8; i++) A3[i] = *(const bf16x8*)(W3f + (i * 64 + lane) * 8);
  }

  float sS0 = 0.f, sS1 = 0.f, sS20 = 0.f, sS21 = 0.f;
  float mx0 = -3.4e38f, mx1 = -3.4e38f, mn0 = 3.4e38f, mn1 = 3.4e38f;

#pragma unroll
  for (int tl = 0; tl < 4; tl++) {
    // layer2 MFMA
    bf16x8 bf2[2];
#pragma unroll
    for (int kc = 0; kc < 2; kc++)
      bf2[kc] = *(const bf16x8*)&x1f[w][kc][q][tl * 16 + n][0];
    f32x4 acc2[MT2];
#pragma unroll
    for (int mt = 0; mt < MT2; mt++) acc2[mt] = *(const f32x4*)(b2 + mt * 16 + q * 4);
#pragma unroll
    for (int kc = 0; kc < 2; kc++)
#pragma unroll
      for (int mt = 0; mt < MT2; mt++)
        acc2[mt] = __builtin_amdgcn_mfma_f32_16x16x32_bf16(A2[kc * MT2 + mt], bf2[kc],
                                                           acc2[mt], 0, 0, 0);
    if (NL == 2) {
      // pre-BN layer2 -> scratch
#pragma unroll
      for (int mt = 0; mt < MT2; mt++) {
        int ch0 = mt * 16 + q * 4;
        *(uint2*)&x3s[w][n][ch0] = make_uint2(packbf(acc2[mt][0], acc2[mt][1]),
                                              packbf(acc2[mt][2], acc2[mt][3]));
      }
    } else {
      // bn2relu -> x2f B-frag rows
#pragma unroll
      for (int mt = 0; mt < MT2; mt++) {
        int ch0 = mt * 16 + q * 4;
        f32x4 ca = *(const f32x4*)(cA2 + ch0);
        f32x4 cc = *(const f32x4*)(cC2 + ch0);
        float r0 = fmaxf(0.f, fmaf(ca[0], acc2[mt][0], cc[0]));
        float r1 = fmaxf(0.f, fmaf(ca[1], acc2[mt][1], cc[1]));
        float r2 = fmaxf(0.f, fmaf(ca[2], acc2[mt][2], cc[2]));
        float r3 = fmaxf(0.f, fmaf(ca[3], acc2[mt][3], cc[3]));
        int kc2 = ch0 >> 5, q2 = (ch0 >> 3) & 3, j0 = ch0 & 7;
        *(uint2*)&x2f[w][kc2][q2][n][j0] = make_uint2(packbf(r0, r1), packbf(r2, r3));
      }
      asm volatile("s_waitcnt lgkmcnt(0)" ::: "memory");
      // layer3 MFMA
      f32x4 acc3[8];
#pragma unroll
      for (int mt = 0; mt < 8; mt++) acc3[mt] = *(const f32x4*)(b3 + mt * 16 + q * 4);
#pragma unroll
      for (int kc = 0; kc < KC3; kc++) {
        bf16x8 bf3 = *(const bf16x8*)&x2f[w][kc][q][n][0];
#pragma unroll
        for (int mt = 0; mt < 8; mt++)
          acc3[mt] = __builtin_amdgcn_mfma_f32_16x16x32_bf16(A3[kc * 8 + mt], bf3,
                                                             acc3[mt], 0, 0, 0);
      }
      // pre-BN layer3 -> scratch
#pragma unroll
      for (int mt = 0; mt < 8; mt++) {
        int ch0 = mt * 16 + q * 4;
        *(uint2*)&x3s[w][n][ch0] = make_uint2(packbf(acc3[mt][0], acc3[mt][1]),
                                              packbf(acc3[mt][2], acc3[mt][3]));
      }
    }
    asm volatile("s_waitcnt lgkmcnt(0)" ::: "memory");
    // readback reduce: this lane owns channels (2*lane, 2*lane+1)
    if (2 * lane < CLs) {
#pragma unroll
      for (int pos = 0; pos < 16; pos++) {
        uint32_t u = *(const uint32_t*)&x3s[w][pos][2 * lane];
        float v0 = __uint_as_float(u << 16);
        float v1v = __uint_as_float(u & 0xffff0000u);
        sS0 += v0;  sS20 = fmaf(v0, v0, sS20);
        sS1 += v1v; sS21 = fmaf(v1v, v1v, sS21);
        if (NL == 3) {
          mx0 = fmaxf(mx0, v0);  mn0 = fminf(mn0, v0);
          mx1 = fmaxf(mx1, v1v); mn1 = fminf(mn1, v1v);
        }
      }
    }
    if (NL == 3) {
      bool fl = (K == 64) ? (tl == 3) : ((tl & 1) == 1);
      if (fl) {
        int center = (K == 64) ? (blockIdx.x * 4 + w)
                               : (blockIdx.x * 8 + w * 2 + (tl >> 1));
        // bf16 store (lossless; verified R6)
        *(uint32_t*)&maxbuf[(size_t)center * 128 + 2 * lane] = packbf(mx0, mx1);
        *(uint32_t*)&minbuf[(size_t)center * 128 + 2 * lane] = packbf(mn0, mn1);
        mx0 = mx1 = -3.4e38f; mn0 = mn1 = 3.4e38f;
      }
    }
    asm volatile("s_waitcnt lgkmcnt(0)" ::: "memory");   // scratch reuse next tl
  }

  // ---- stats: per-wave LDS row, then one slotted flush per block ----
  {
    int ch = 2 * lane;
    if (ch < CLs) {
      sAccW[w][ch] = sS0;        sAccW[w][ch + 1] = sS1;
      sAccW[w][CLs + ch] = sS20; sAccW[w][CLs + ch + 1] = sS21;
    }
  }
  __syncthreads();
  float* dst = stats + (size_t)(blockIdx.x & (NSLOT - 1)) * (2 * CLs);
  for (int i = t; i < 2 * CLs; i += 256)
    atomicAdd(&dst[i], sAccW[0][i] + sAccW[1][i] + sAccW[2][i] + sAccW[3][i]);
}

// ---------------- BN coeffs from slotted stats, both scales in one launch ----------------
__global__ void finalize2_kernel(const float* __restrict__ st0, const float* __restrict__ g0,
                                 const float* __restrict__ be0, float invP0,
                                 float* __restrict__ cAo0, float* __restrict__ cCo0, int C0,
                                 const float* __restrict__ st1, const float* __restrict__ g1,
                                 const float* __restrict__ be1, float invP1,
                                 float* __restrict__ cAo1, float* __restrict__ cCo1, int C1) {
  const float* st = blockIdx.x ? st1 : st0;
  const float* g  = blockIdx.x ? g1  : g0;
  const float* be = blockIdx.x ? be1 : be0;
  float invP = blockIdx.x ? invP1 : invP0;
  float* cA = blockIdx.x ? cAo1 : cAo0;
  float* cC = blockIdx.x ? cCo1 : cCo0;
  int C = blockIdx.x ? C1 : C0;
  int t = threadIdx.x;
  if (t < C) {
    float s = 0.f, s2 = 0.f;
    for (int sl = 0; sl < NSLOT; sl++) {
      s  += st[sl * 2 * C + t];
      s2 += st[sl * 2 * C + C + t];
    }
    float mu = s * invP;
    float var = fmaf(s2, invP, -(mu * mu));
    float a = g[t] / sqrtf(var + 1e-5f);
    cA[t] = a;
    cC[t] = fmaf(-a, mu, be[t]);
  }
}

// ---------------- final output: affine(max/min by sign) + relu, transposed write ----------------
// Both scales in one launch; reads the bf16 max/min buffers (expand via <<16).
__global__ __launch_bounds__(256) void outwrite_fused(
    const ushort* __restrict__ mx0buf, const ushort* __restrict__ mn0buf,
    const ushort* __restrict__ mx1buf, const ushort* __restrict__ mn1buf,
    const float* __restrict__ coef, float* __restrict__ out_feat) {
  __shared__ float tile[64 * 130];
  int bx = blockIdx.x;
  const ushort* mxb; const ushort* mnb; const float* cA3; const float* cC3;
  int chOff, c0;
  if (bx < BM / 64) {
    mxb = mx0buf; mnb = mn0buf; cA3 = coef + 512; cC3 = coef + 640;
    chOff = 0; c0 = bx * 64;
  } else {
    mxb = mx1buf; mnb = mn1buf; cA3 = coef + 768 + 512; cC3 = coef + 768 + 640;
    chOff = 128; c0 = (bx - BM / 64) * 64;
  }
  int t = threadIdx.x;
#pragma unroll
  for (int i = 0; i < 32; i++) {
    int e = i * 256 + t;
    int lc = e >> 7, o = e & 127;
    float a = cA3[o];
    float mv = __uint_as_float(((uint32_t)mxb[(size_t)(c0 + lc) * 128 + o]) << 16);
    float nv = __uint_as_float(((uint32_t)mnb[(size_t)(c0 + lc) * 128 + o]) << 16);
    float v = (a >= 0.f) ? fmaf(a, mv, cC3[o]) : fmaf(a, nv, cC3[o]);
    tile[lc * 130 + o] = fmaxf(v, 0.f);
  }
  __syncthreads();
  int b = c0 >> 10, m0 = c0 & 1023;
#pragma unroll
  for (int j = 0; j < 32; j++) {
    int e = j * 256 + t;
    int lm = e & 63, o = e >> 6;
    out_feat[((size_t)(b * 256 + chOff + o)) * MCTR + m0 + lm] = tile[lm * 130 + o];
  }
}

// ======================= host launch =======================
extern "C" void kernel_launch(void* const* d_in, const int* in_sizes, int n_in,
                              void* d_out, int out_size, void* d_ws, size_t ws_size,
                              hipStream_t stream) {
  (void)in_sizes; (void)n_in; (void)out_size;
  const float* pc   = (const float*)d_in[0];
  const float* feat = (const float*)d_in[1];
  const float *Wp[2][3], *bp[2][3], *gp[2][3], *bep[2][3];
  for (int s = 0; s < 2; s++)
    for (int l = 0; l < 3; l++) {
      int base = 2 + (s * 3 + l) * 4;
      Wp[s][l]  = (const float*)d_in[base + 0];
      bp[s][l]  = (const float*)d_in[base + 1];
      gp[s][l]  = (const float*)d_in[base + 2];
      bep[s][l] = (const float*)d_in[base + 3];
    }

  char* ws = (char*)d_ws;
  float*  statsR  = (float*) (ws + 0x10000);     // 6 x NSLOT x 256 f32 = 192 KB
  float*  coef    = (float*) (ws + 0x40000);     // 2 scales x 768 f32
  float*  wt      = (float*) (ws + 0x42000);     // 8576 f32
  ushort* wf      = (ushort*)(ws + 0x50000);     // 60 KB bf16 A-frags
  ushort* Ub0     = (ushort*)(ws + 0x100000);    // 8 MB [b][n][64] bf16
  ushort* Ub1     = (ushort*)(ws + 0x900000);    // 8 MB
  int*    gidx0   = (int*)   (ws + 0x1100000);   // 2 MB
  int*    gidx1   = (int*)   (ws + 0x1300000);   // 4 MB
  ushort* mxb0    = (ushort*)(ws + 0x1700000);   // 4 MB bf16 [center][128]
  ushort* mnb0    = (ushort*)(ws + 0x1B00000);   // 4 MB
  ushort* mxb1    = (ushort*)(ws + 0x1F00000);   // 4 MB
  ushort* mnb1    = (ushort*)(ws + 0x2300000);   // 4 MB
  const unsigned long long WS_NEEDED = 0x2700000ULL;   // ~39.3 MB
  if (ws_size < WS_NEEDED) {
    fprintf(stderr, "[kernel] ws too small: %zu < %llu\n", ws_size, WS_NEEDED);
    return;
  }
  float* cf0 = coef, *cf1 = coef + 768;
  // per scale: cA1@0 cC1@128 cA2@256 cC2@384 cA3@512 cC3@640

  float* out_newpc = (float*)d_out;
  float* out_feat  = (float*)d_out + (size_t)BATCH * 3 * MCTR;

  const int P0 = BM * 32, P1 = BM * 64;
  const int LSTRIDE = NSLOT * 256;
  float* st10 = statsR + 0 * LSTRIDE, *st20 = statsR + 1 * LSTRIDE, *st30 = statsR + 2 * LSTRIDE;
  float* st11 = statsR + 3 * LSTRIDE, *st21 = statsR + 4 * LSTRIDE, *st31 = statsR + 5 * LSTRIDE;

  hipMemsetAsync(statsR, 0, 6 * NSLOT * 256 * sizeof(float), stream);
  // fused: FPS (blocks 0-15) || U0 (16-271) || U1 (272-527) || prep (528-681)
  fused_stageA<<<682, 256, 0, stream>>>(pc, feat,
                                        Wp[0][0], bp[0][0], Wp[0][1], Wp[0][2],
                                        Wp[1][0], bp[1][0], Wp[1][1], Wp[1][2],
                                        out_newpc, Ub0, Ub1, wt, wf);
  ballq_fused<<<BM / 2, 256, 0, stream>>>(pc, out_newpc, gidx0, gidx1,
                                          (float)(0.1 * 0.1), (float)(0.2 * 0.2));

  l1_fused<<<P0 / 128 + P1 / 128, 128, 0, stream>>>(Ub0, Ub1, pc, out_newpc,
                                                    gidx0, gidx1,
                                                    wt + 4096, wt + 8384, st10, st11);
  finalize2_kernel<<<2, 128, 0, stream>>>(st10, gp[0][0], bep[0][0], 1.0f / P0,
                                          cf0 + 0, cf0 + 128, 64,
                                          st11, gp[1][0], bep[1][0], 1.0f / P1,
                                          cf1 + 0, cf1 + 128, 64);

  mfma_pass<32, 64, 2><<<P0 / 256, 256, 0, stream>>>(Ub0, pc, out_newpc, gidx0,
      wt + 4096, wf + 0, wf + 4096, bp[0][1], bp[0][2],
      cf0 + 0, cf0 + 128, nullptr, nullptr, st20, nullptr, nullptr);
  mfma_pass<64, 96, 2><<<P1 / 256, 256, 0, stream>>>(Ub1, pc, out_newpc, gidx1,
      wt + 8384, wf + 12288, wf + 18432, bp[1][1], bp[1][2],
      cf1 + 0, cf1 + 128, nullptr, nullptr, st21, nullptr, nullptr);
  finalize2_kernel<<<2, 128, 0, stream>>>(st20, gp[0][1], bep[0][1], 1.0f / P0,
                                          cf0 + 256, cf0 + 384, 64,
                                          st21, gp[1][1], bep[1][1], 1.0f / P1,
                                          cf1 + 256, cf1 + 384, 96);

  mfma_pass<32, 64, 3><<<P0 / 256, 256, 0, stream>>>(Ub0, pc, out_newpc, gidx0,
      wt + 4096, wf + 0, wf + 4096, bp[0][1], bp[0][2],
      cf0 + 0, cf0 + 128, cf0 + 256, cf0 + 384, st30, mxb0, mnb0);
  mfma_pass<64, 96, 3><<<P1 / 256, 256, 0, stream>>>(Ub1, pc, out_newpc, gidx1,
      wt + 8384, wf + 12288, wf + 18432, bp[1][1], bp[1][2],
      cf1 + 0, cf1 + 128, cf1 + 256, cf1 + 384, st31, mxb1, mnb1);
  finalize2_kernel<<<2, 128, 0, stream>>>(st30, gp[0][2], bep[0][2], 1.0f / P0,
                                          cf0 + 512, cf0 + 640, 128,
                                          st31, gp[1][2], bep[1][2], 1.0f / P1,
                                          cf1 + 512, cf1 + 640, 128);
  // both output writes in one launch
  outwrite_fused<<<2 * (BM / 64), 256, 0, stream>>>(mxb0, mnb0, mxb1, mnb1,
                                                    coef, out_feat);
}

// Round 10
// 1125.874 us; speedup vs baseline: 1.0767x; 1.0536x over previous
//
#include <hip/hip_runtime.h>
#include <cstdio>
#include <cstdint>

// PointNet++ SA module, MI355X. Recompute pipeline; layers 2/3 on MFMA (bf16).
// B=16, N=4096, M=1024; scale0: r=0.1,K=32,[67,64,64,128]; scale1: r=0.2,K=64,[67,64,96,128]
// Best measured: R9 = 1186.2us (R7 config). This round: BN-coeff finalize
// kernels inlined into consumers (bit-exact; removes 3 launches + 4 tiny
// dispatches from the serial chain). Everything else byte-identical to R9.

constexpr int BATCH = 16, NPTS = 4096, MCTR = 1024;
constexpr int BM = BATCH * MCTR;   // 16384 centers
constexpr int NSLOT = 32;          // stats contention-spreading slots

typedef short bf16x8 __attribute__((ext_vector_type(8)));
typedef float f32x4  __attribute__((ext_vector_type(4)));
typedef float f32x2  __attribute__((ext_vector_type(2)));

__device__ __forceinline__ ushort f2bf(float f) {
  uint32_t u = __float_as_uint(f);
  u += 0x7fffu + ((u >> 16) & 1u);   // RNE
  return (ushort)(u >> 16);
}
__device__ __forceinline__ uint32_t packbf(float a, float b) {
  return (uint32_t)f2bf(a) | ((uint32_t)f2bf(b) << 16);
}
__device__ __forceinline__ unsigned long long umax64(unsigned long long a,
                                                     unsigned long long b) {
  return (a > b) ? a : b;
}

// DPP-based max over u64 keys (old=0 is identity: keys are non-negative).
//  0xB1 xor1, 0x4E xor2, 0x124 row_ror:4, 0x128 row_ror:8 -> row max;
//  0x142 row_bcast15, 0x143 row_bcast31 -> lane 63 = full wave max. [proven]
template <int CTRL>
__device__ __forceinline__ unsigned long long dpp_max(unsigned long long k) {
  int lo = (int)(uint32_t)k, hi = (int)(uint32_t)(k >> 32);
  uint32_t plo = (uint32_t)__builtin_amdgcn_update_dpp(0, lo, CTRL, 0xf, 0xf, false);
  uint32_t phi = (uint32_t)__builtin_amdgcn_update_dpp(0, hi, CTRL, 0xf, 0xf, false);
  unsigned long long pk = ((unsigned long long)phi << 32) | plo;
  return (pk > k) ? pk : k;
}

// ---------------- farthest point sampling (device body, fused kernel) ----------------
// PROVEN version (R3/R7/R9, 611-615us inside stageA). 256-thread block per
// batch, 16 pts/thread as float2 pairs (packed math; contract(off) keeps
// mul/add order bit-exact vs ref). Per iter: centroid LDS fetch -> 8x2-pt
// packed update (serial f32 select chain) -> 6-stage DPP wave reduce (lane63 =
// wave max) -> 4 keys to LDS (double-buffered) -> ONE barrier -> 2x b128
// readback + umax64 tree. NO global stores in the loop.
// FAILED ALTERNATIVES (do not retry without new evidence) — empirical local
// optimum after 5 attempts:
//  - 1024-thr block + per-lane readback (R1): replay-divergence tripwire.
//  - same-kernel spin-wait ballq consumers (R4): LDS-capped convoy, +554us.
//  - coord-carry through the selection chain + 64b-DPP readback (R5): +250us.
//  - u64-key selection tree + candidate-coords overlap (R8): +15us (issue
//    count matters as much as dependency depth here).
__device__ __forceinline__ void fps_body(int b, int t, const float* __restrict__ pc,
                                         float* __restrict__ newpc_out,
                                         char* __restrict__ smem) {
  float* lX = (float*)smem;
  float* lY = lX + NPTS;
  float* lZ = lY + NPTS;
  int*   sampL = (int*)(smem + 3 * NPTS * 4);                       // 4 KB
  unsigned long long* wkey =
      (unsigned long long*)(smem + 3 * NPTS * 4 + MCTR * 4);        // 2 x 4 keys
  const int lane = t & 63;
  const int w = t >> 6;
  const float* px = pc + (size_t)b * 3 * NPTS;
  f32x2 X2[8], Y2[8], Z2[8], D2[8];
#pragma unroll
  for (int j = 0; j < 16; j++) {
    int p = t + 256 * j;
    float x = px[p], y = px[NPTS + p], z = px[2 * NPTS + p];
    X2[j >> 1][j & 1] = x; Y2[j >> 1][j & 1] = y; Z2[j >> 1][j & 1] = z;
    D2[j >> 1][j & 1] = 1e10f;
    lX[p] = x; lY[p] = y; lZ[p] = z;
  }
  if (t == 0) sampL[0] = 0;
  __syncthreads();
  int far = 0;
  for (int it = 1; it < MCTR; it++) {
    float cx = lX[far], cy = lY[far], cz = lZ[far];
    float bv = -1.0f; int bi = 0;
    {
#pragma clang fp contract(off)
      f32x2 cx2 = {cx, cx}, cy2 = {cy, cy}, cz2 = {cz, cz};
#pragma unroll
      for (int j2 = 0; j2 < 8; j2++) {
        f32x2 dx = X2[j2] - cx2, dy = Y2[j2] - cy2, dz = Z2[j2] - cz2;
        f32x2 d = dx * dx + dy * dy + dz * dz;   // ((x^2+y^2)+z^2), no fma
        f32x2 dm;
        dm[0] = fminf(D2[j2][0], d[0]);
        dm[1] = fminf(D2[j2][1], d[1]);
        D2[j2] = dm;
        // ascending point order => strict '>' keeps first index within thread
        bool g0 = dm[0] > bv;
        bv = g0 ? dm[0] : bv; bi = g0 ? t + 256 * (2 * j2) : bi;
        bool g1 = dm[1] > bv;
        bv = g1 ? dm[1] : bv; bi = g1 ? t + 256 * (2 * j2 + 1) : bi;
      }
    }
    // d >= 0 => sign clear => uint order == float order; ~idx => first-index ties
    unsigned long long key =
        ((unsigned long long)__float_as_uint(bv) << 32) | (unsigned)(~bi);
    key = dpp_max<0xB1>(key);    // xor 1
    key = dpp_max<0x4E>(key);    // xor 2
    key = dpp_max<0x124>(key);   // row_ror:4
    key = dpp_max<0x128>(key);   // row_ror:8   -> row max in all 16 lanes
    key = dpp_max<0x142>(key);   // row_bcast15
    key = dpp_max<0x143>(key);   // row_bcast31 -> lane 63 = full wave max
    if (lane == 63) wkey[(it & 1) * 4 + w] = key;
    __syncthreads();
    const ulonglong2* kp = (const ulonglong2*)(wkey + (it & 1) * 4);
    ulonglong2 k0 = kp[0], k1 = kp[1];
    unsigned long long kk = umax64(umax64(k0.x, k0.y), umax64(k1.x, k1.y));
    far = (int)(~(unsigned)kk);
    if (t == 0) sampL[it] = far;
  }
  __syncthreads();
  float* npc = newpc_out + (size_t)b * 3 * MCTR;
  for (int m = t; m < MCTR; m += 256) {
    int f = sampL[m];
    npc[m] = lX[f]; npc[MCTR + m] = lY[f]; npc[2 * MCTR + m] = lZ[f];
  }
}

// ---------------- U = bf16(W_feat . feat + b1) (device body, fused kernel) --------
__device__ __forceinline__ void u_body(const float* __restrict__ feat,
                                       const float* __restrict__ W,
                                       const float* __restrict__ bias,
                                       ushort* __restrict__ Ub, int ub,
                                       char* __restrict__ smem) {
  float* wl = (float*)smem;          // wl[c*64+o] = W[o*67+3+c]
  int t = threadIdx.x;
#pragma unroll
  for (int i = 0; i < 16; i++) {
    int r = t + 256 * i;
    wl[r] = W[(r & 63) * 67 + 3 + (r >> 6)];
  }
  __syncthreads();
  int gid = ub * 256 + t;
  int b = gid >> 12, n = gid & 4095;
  float acc[64];
#pragma unroll
  for (int o = 0; o < 64; o++) acc[o] = bias[o];
  const float* fb = feat + (size_t)b * 64 * NPTS + n;
  for (int c = 0; c < 64; c++) {
    float x = fb[(size_t)c * NPTS];
    const f32x4* w4 = (const f32x4*)(wl + c * 64);
#pragma unroll
    for (int q = 0; q < 16; q++) {
      f32x4 wv = w4[q];
      acc[4 * q + 0] = fmaf(wv[0], x, acc[4 * q + 0]);
      acc[4 * q + 1] = fmaf(wv[1], x, acc[4 * q + 1]);
      acc[4 * q + 2] = fmaf(wv[2], x, acc[4 * q + 2]);
      acc[4 * q + 3] = fmaf(wv[3], x, acc[4 * q + 3]);
    }
  }
  uint4* o4 = (uint4*)(Ub + (size_t)gid * 64);
#pragma unroll
  for (int qq = 0; qq < 8; qq++)
    o4[qq] = make_uint4(packbf(acc[8*qq+0], acc[8*qq+1]), packbf(acc[8*qq+2], acc[8*qq+3]),
                        packbf(acc[8*qq+4], acc[8*qq+5]), packbf(acc[8*qq+6], acc[8*qq+7]));
}

// ---------------- fused stage A: FPS (16) | U0 (256) | U1 (256) | prep (154) ------
__global__ __launch_bounds__(256) void fused_stageA(
    const float* __restrict__ pc, const float* __restrict__ feat,
    const float* __restrict__ W00, const float* __restrict__ b00,
    const float* __restrict__ W01, const float* __restrict__ W02,
    const float* __restrict__ W10, const float* __restrict__ b10,
    const float* __restrict__ W11, const float* __restrict__ W12,
    float* __restrict__ newpc_out, ushort* __restrict__ Ub0,
    ushort* __restrict__ Ub1, float* __restrict__ wt, ushort* __restrict__ wf) {
  __shared__ __align__(16) char smem[3 * NPTS * 4 + MCTR * 4 + 64];   // 53312 B
  int bx = blockIdx.x, t = threadIdx.x;
  if (bx < 16) { fps_body(bx, t, pc, newpc_out, smem); return; }
  if (bx < 528) {
    int ub = bx - 16;
    if (ub < 256) u_body(feat, W00, b00, Ub0, ub, smem);
    else          u_body(feat, W10, b10, Ub1, ub - 256, smem);
    return;
  }
  // wt (float): WtF0@0(4096,unused) Wt1x0@4096(192) WtF1@4288(4096,unused) Wt1x1@8384(192)
  // wf (ushort): W2f0@0(4096) W3f0@4096(8192) W2f1@12288(6144) W3f1@18432(12288)
  int e = (bx - 528) * 256 + t;
  if (e < 4096) { wt[e] = W00[(e & 63) * 67 + 3 + (e >> 6)]; return; }
  if (e < 4288) { int r = e - 4096; wt[e] = W00[(r & 63) * 67 + (r >> 6)]; return; }
  if (e < 8384) { int r = e - 4288; wt[e] = W10[(r & 63) * 67 + 3 + (r >> 6)]; return; }
  if (e < 8576) { int r = e - 8384; wt[e] = W10[(r & 63) * 67 + (r >> 6)]; return; }
  int e2 = e - 8576;
  if (e2 >= 30720) return;
  const float* W; int CIN, MT, off;
  if (e2 < 4096)       { W = W01; CIN = 64; MT = 4; off = 0; }
  else if (e2 < 12288) { W = W02; CIN = 64; MT = 8; off = 4096; }
  else if (e2 < 18432) { W = W11; CIN = 64; MT = 6; off = 12288; }
  else                 { W = W12; CIN = 96; MT = 8; off = 18432; }
  int r = e2 - off;
  int j = r & 7, lane = (r >> 3) & 63, fm = r >> 9;
  int kc = fm / MT, mt = fm % MT;
  int out_ch = mt * 16 + (lane & 15);
  int in_ch  = kc * 32 + (lane >> 4) * 8 + j;
  wf[e2] = f2bf(W[out_ch * CIN + in_ch]);
}

// ---------------- ball query: wave per center, ballot-ranked first-K ----------------
template <int K>
__device__ __forceinline__ void ballq_body(int bx, const float* __restrict__ pc,
                                           const float* __restrict__ newpc,
                                           int* __restrict__ gidx, float r2) {
  int lane = threadIdx.x & 63;
  int wave = threadIdx.x >> 6;
  int center = bx * 4 + wave;
  int b = center >> 10, m = center & 1023;
  const float* nb = newpc + (size_t)b * 3 * MCTR + m;
  float cx = nb[0], cy = nb[MCTR], cz = nb[2 * MCTR];
  const float* px = pc + (size_t)b * 3 * NPTS;
  int cnt = 0;
  int firstn = 0x7fffffff;
  for (int chunk = 0; chunk < NPTS / 64 && cnt < K; chunk++) {
    int n = chunk * 64 + lane;
    float dx = __fsub_rn(cx, px[n]);
    float dy = __fsub_rn(cy, px[NPTS + n]);
    float dz = __fsub_rn(cz, px[2 * NPTS + n]);
    float d2 = __fadd_rn(__fadd_rn(__fmul_rn(dx, dx), __fmul_rn(dy, dy)), __fmul_rn(dz, dz));
    bool in = d2 < r2;
    unsigned long long ball = __ballot(in);
    int pos = cnt + (int)__popcll(ball & ((1ull << lane) - 1ull));
    if (in && pos < K) gidx[(size_t)center * K + pos] = n;
    if (in && pos == 0) firstn = n;
    cnt += (int)__popcll(ball);
  }
#pragma unroll
  for (int off = 32; off; off >>= 1) firstn = min(firstn, __shfl_xor(firstn, off));
  if (lane < K && lane >= cnt) gidx[(size_t)center * K + lane] = firstn;
}

__global__ __launch_bounds__(256) void ballq_fused(const float* __restrict__ pc,
                                                   const float* __restrict__ newpc,
                                                   int* __restrict__ gidx0,
                                                   int* __restrict__ gidx1,
                                                   float r2a, float r2b) {
  int bx = blockIdx.x;
  if (bx < BM / 4) ballq_body<32>(bx, pc, newpc, gidx0, r2a);
  else             ballq_body<64>(bx - BM / 4, pc, newpc, gidx1, r2b);
}

// ---------------- bf16 U gather + layer1 (shared by l1 / mfma_pass) ----------------
__device__ __forceinline__ void layer1_compute(const ushort* __restrict__ Ub,
                                               const float* __restrict__ pc,
                                               const float* __restrict__ newpc,
                                               const float* __restrict__ Wt1,
                                               int b, int m, int idx, float* v1) {
  float dx = pc[((size_t)b * 3 + 0) * NPTS + idx] - newpc[((size_t)b * 3 + 0) * MCTR + m];
  float dy = pc[((size_t)b * 3 + 1) * NPTS + idx] - newpc[((size_t)b * 3 + 1) * MCTR + m];
  float dz = pc[((size_t)b * 3 + 2) * NPTS + idx] - newpc[((size_t)b * 3 + 2) * MCTR + m];
  const uint4* u4 = (const uint4*)(Ub + (size_t)((b << 12) + idx) * 64);
#pragma unroll
  for (int qq = 0; qq < 8; qq++) {
    uint4 u = u4[qq];
    v1[8*qq+0] = __uint_as_float(u.x << 16);
    v1[8*qq+1] = __uint_as_float(u.x & 0xffff0000u);
    v1[8*qq+2] = __uint_as_float(u.y << 16);
    v1[8*qq+3] = __uint_as_float(u.y & 0xffff0000u);
    v1[8*qq+4] = __uint_as_float(u.z << 16);
    v1[8*qq+5] = __uint_as_float(u.z & 0xffff0000u);
    v1[8*qq+6] = __uint_as_float(u.w << 16);
    v1[8*qq+7] = __uint_as_float(u.w & 0xffff0000u);
  }
#pragma unroll
  for (int o = 0; o < 64; o++) v1[o] = fmaf(Wt1[o], dx, v1[o]);
#pragma unroll
  for (int o = 0; o < 64; o++) v1[o] = fmaf(Wt1[64 + o], dy, v1[o]);
#pragma unroll
  for (int o = 0; o < 64; o++) v1[o] = fmaf(Wt1[128 + o], dz, v1[o]);
}

// ---------------- layer-1 stats pass (VALU; cheap) ----------------
__device__ __forceinline__ void wave_reduce32(const float* vals, float* tile, int t,
                                              float* swrow, int co) {
  float* myrow = tile + t * 32;
  int rsw = t & 31;
#pragma unroll
  for (int o = 0; o < 32; o++) myrow[o ^ rsw] = vals[o];
  __syncthreads();
  int lane = t & 63;
  int ch = lane & 31, sub = lane >> 5;
  const float* base = tile + (t & ~63) * 32;
  float s = 0.f, s2 = 0.f;
#pragma unroll
  for (int r = 0; r < 32; r++) {
    int row = sub * 32 + r;
    float v = base[row * 32 + (ch ^ (row & 31))];
    s += v; s2 = fmaf(v, v, s2);
  }
  float st = s + __shfl_xor(s, 32);
  float st2 = s2 + __shfl_xor(s2, 32);
  if (sub == 0) {
    swrow[co + ch] += st;
    swrow[128 + co + ch] += st2;
  }
  __syncthreads();
}

template <int K>
__device__ __forceinline__ void l1_body(
    int bx, const ushort* __restrict__ Ub, const float* __restrict__ pc,
    const float* __restrict__ newpc, const int* __restrict__ gidx,
    const float* __restrict__ Wt1, float* __restrict__ stats,
    float* tile, float* sAcc /* [2][256] flat */) {
  const int t = threadIdx.x;
  const int w = t >> 6;
  const int p = bx * 128 + t;
  const int bm = p / K;
  const int b = bm >> 10, m = bm & 1023;
  const int idx = gidx[p];
  for (int i = t; i < 512; i += 128) sAcc[i] = 0.f;

  float v1[64];
  layer1_compute(Ub, pc, newpc, Wt1, b, m, idx, v1);

  wave_reduce32(v1,      tile, t, sAcc + w * 256, 0);
  wave_reduce32(v1 + 32, tile, t, sAcc + w * 256, 32);

  __syncthreads();
  float* dst = stats + (size_t)(bx & (NSLOT - 1)) * 128;
  for (int i = t; i < 64; i += 128) {
    atomicAdd(&dst[i],      sAcc[i]       + sAcc[256 + i]);
    atomicAdd(&dst[64 + i], sAcc[128 + i] + sAcc[256 + 128 + i]);
  }
}

__global__ __launch_bounds__(128, 2) void l1_fused(
    const ushort* __restrict__ Ub0, const ushort* __restrict__ Ub1,
    const float* __restrict__ pc, const float* __restrict__ newpc,
    const int* __restrict__ gidx0, const int* __restrict__ gidx1,
    const float* __restrict__ Wt1a, const float* __restrict__ Wt1b,
    float* __restrict__ st0, float* __restrict__ st1) {
  __shared__ float tile[128 * 32];
  __shared__ float sAccW[2][256];
  constexpr int NB0 = (BM * 32) / 128;
  int bx = blockIdx.x;
  if (bx < NB0) l1_body<32>(bx, Ub0, pc, newpc, gidx0, Wt1a, st0, tile, &sAccW[0][0]);
  else          l1_body<64>(bx - NB0, Ub1, pc, newpc, gidx1, Wt1b, st1, tile, &sAccW[0][0]);
}

// ---------------- MFMA MLP pass: layer1 (VALU) -> layer2[/3] (MFMA) ----------------
// SEPARATE kernel per scale with OWN typed __shared__ arrays (R6 lesson: no
// char[] LDS blobs — defeats alias analysis, +244us).
// R10: BN coefficients computed INLINE from the stats buffers (identical
// arithmetic to the removed finalize2_kernel — bit-exact; stream order
// guarantees stats completeness). invP applies to both BN1 and BN2 (same
// point count P per scale).
// NL=2: stats of pre-BN layer2.  NL=3: stats of pre-BN layer3 + per-center
// max/min stored as bf16 (lossless — verified R6).
template <int K, int C2, int NL>
__global__ __launch_bounds__(256, 2) void mfma_pass(
    const ushort* __restrict__ Ub, const float* __restrict__ pc,
    const float* __restrict__ newpc, const int* __restrict__ gidx,
    const float* __restrict__ Wt1,
    const ushort* __restrict__ W2f, const ushort* __restrict__ W3f,
    const float* __restrict__ b2, const float* __restrict__ b3,
    const float* __restrict__ st1, const float* __restrict__ g1,
    const float* __restrict__ be1,
    const float* __restrict__ st2, const float* __restrict__ g2,
    const float* __restrict__ be2, float invP,
    float* __restrict__ stats, ushort* __restrict__ maxbuf,
    ushort* __restrict__ minbuf) {
  constexpr int MT2 = C2 / 16, KC3 = C2 / 32;
  constexpr int CLs = (NL == 2) ? C2 : 128;
  constexpr int SSTR = CLs + 4;                       // scratch row stride (ushorts)
  __shared__ __align__(16) ushort x1f[4][2][4][64][8];         // 32 KB, B-frag order
  __shared__ __align__(16) ushort x2f[(NL == 3) ? 4 : 1][KC3][4][16][8];
  __shared__ __align__(16) ushort x3s[4][16][SSTR];            // pre-BN scratch rows
  __shared__ float sAccW[4][256];
  __shared__ __align__(16) float cA1s[64], cC1s[64];
  __shared__ __align__(16) float cA2s[(NL == 3) ? C2 : 4], cC2s[(NL == 3) ? C2 : 4];

  const int t = threadIdx.x, w = t >> 6, lane = t & 63;
  const int q = lane >> 4, n = lane & 15;
  const int p = blockIdx.x * 256 + t;
  const int bm = p / K;
  const int b = bm >> 10, m = bm & 1023;
  const int idx = gidx[p];

  // ---- inline BN-coeff finalize (bit-exact vs old finalize2_kernel) ----
  if (t < 64) {
    float s = 0.f, s2 = 0.f;
    for (int sl = 0; sl < NSLOT; sl++) {
      s  += st1[sl * 128 + t];
      s2 += st1[sl * 128 + 64 + t];
    }
    float mu = s * invP;
    float var = fmaf(s2, invP, -(mu * mu));
    float a = g1[t] / sqrtf(var + 1e-5f);
    cA1s[t] = a;
    cC1s[t] = fmaf(-a, mu, be1[t]);
  }
  if (NL == 3 && t >= 128 && t < 128 + C2) {
    int c = t - 128;
    float s = 0.f, s2 = 0.f;
    for (int sl = 0; sl < NSLOT; sl++) {
      s  += st2[sl * 2 * C2 + c];
      s2 += st2[sl * 2 * C2 + C2 + c];
    }
    float mu = s * invP;
    float var = fmaf(s2, invP, -(mu * mu));
    float a = g2[c] / sqrtf(var + 1e-5f);
    cA2s[c] = a;
    cC2s[c] = fmaf(-a, mu, be2[c]);
  }
  __syncthreads();

  // ---- layer1 per-thread (position = t) ----
  {
    float v1[64];
    layer1_compute(Ub, pc, newpc, Wt1, b, m, idx, v1);
    // bn1relu -> x1f B-frag rows (ch = kc*32 + q*8 + j), own 16B slot per thread
    int nw = t & 63;
#pragma unroll
    for (int g = 0; g < 8; g++) {
      uint32_t d0, d1, d2, d3;
      int c = g * 8;
      d0 = packbf(fmaxf(0.f, fmaf(cA1s[c+0], v1[c+0], cC1s[c+0])),
                  fmaxf(0.f, fmaf(cA1s[c+1], v1[c+1], cC1s[c+1])));
      d1 = packbf(fmaxf(0.f, fmaf(cA1s[c+2], v1[c+2], cC1s[c+2])),
                  fmaxf(0.f, fmaf(cA1s[c+3], v1[c+3], cC1s[c+3])));
      d2 = packbf(fmaxf(0.f, fmaf(cA1s[c+4], v1[c+4], cC1s[c+4])),
                  fmaxf(0.f, fmaf(cA1s[c+5], v1[c+5], cC1s[c+5])));
      d3 = packbf(fmaxf(0.f, fmaf(cA1s[c+6], v1[c+6], cC1s[c+6])),
                  fmaxf(0.f, fmaf(cA1s[c+7], v1[c+7], cC1s[c+7])));
      *(uint4*)&x1f[w][g >> 2][g & 3][nw][0] = make_uint4(d0, d1, d2, d3);
    }
  }
  asm volatile("s_waitcnt lgkmcnt(0)" ::: "memory");

  // ---- preload A-fragments into registers ----
  bf16x8 A2[2 * MT2];
#pragma unroll
  for (int i = 0; i < 2 * MT2; i++) A2[i] = *(const bf16x8*)(W2f + (i * 64 + lane) * 8);
  bf16x8 A3[(NL == 3) ? KC3 * 8 : 1];
  if (NL == 3) {
#pragma unroll
    for (int i = 0; i < KC3 * 8; i++) A3[i] = *(const bf16x8*)(W3f + (i * 64 + lane) * 8);
  }

  float sS0 = 0.f, sS1 = 0.f, sS20 = 0.f, sS21 = 0.f;
  float mx0 = -3.4e38f, mx1 = -3.4e38f, mn0 = 3.4e38f, mn1 = 3.4e38f;

#pragma unroll
  for (int tl = 0; tl < 4; tl++) {
    // layer2 MFMA
    bf16x8 bf2[2];
#pragma unroll
    for (int kc = 0; kc < 2; kc++)
      bf2[kc] = *(const bf16x8*)&x1f[w][kc][q][tl * 16 + n][0];
    f32x4 acc2[MT2];
#pragma unroll
    for (int mt = 0; mt < MT2; mt++) acc2[mt] = *(const f32x4*)(b2 + mt * 16 + q * 4);
#pragma unroll
    for (int kc = 0; kc < 2; kc++)
#pragma unroll
      for (int mt = 0; mt < MT2; mt++)
        acc2[mt] = __builtin_amdgcn_mfma_f32_16x16x32_bf16(A2[kc * MT2 + mt], bf2[kc],
                                                           acc2[mt], 0, 0, 0);
    if (NL == 2) {
      // pre-BN layer2 -> scratch
#pragma unroll
      for (int mt = 0; mt < MT2; mt++) {
        int ch0 = mt * 16 + q * 4;
        *(uint2*)&x3s[w][n][ch0] = make_uint2(packbf(acc2[mt][0], acc2[mt][1]),
                                              packbf(acc2[mt][2], acc2[mt][3]));
      }
    } else {
      // bn2relu -> x2f B-frag rows
#pragma unroll
      for (int mt = 0; mt < MT2; mt++) {
        int ch0 = mt * 16 + q * 4;
        f32x4 ca = *(const f32x4*)(cA2s + ch0);
        f32x4 cc = *(const f32x4*)(cC2s + ch0);
        float r0 = fmaxf(0.f, fmaf(ca[0], acc2[mt][0], cc[0]));
        float r1 = fmaxf(0.f, fmaf(ca[1], acc2[mt][1], cc[1]));
        float r2 = fmaxf(0.f, fmaf(ca[2], acc2[mt][2], cc[2]));
        float r3 = fmaxf(0.f, fmaf(ca[3], acc2[mt][3], cc[3]));
        int kc2 = ch0 >> 5, q2 = (ch0 >> 3) & 3, j0 = ch0 & 7;
        *(uint2*)&x2f[w][kc2][q2][n][j0] = make_uint2(packbf(r0, r1), packbf(r2, r3));
      }
      asm volatile("s_waitcnt lgkmcnt(0)" ::: "memory");
      // layer3 MFMA
      f32x4 acc3[8];
#pragma unroll
      for (int mt = 0; mt < 8; mt++) acc3[mt] = *(const f32x4*)(b3 + mt * 16 + q * 4);
#pragma unroll
      for (int kc = 0; kc < KC3; kc++) {
        bf16x8 bf3 = *(const bf16x8*)&x2f[w][kc][q][n][0];
#pragma unroll
        for (int mt = 0; mt < 8; mt++)
          acc3[mt] = __builtin_amdgcn_mfma_f32_16x16x32_bf16(A3[kc * 8 + mt], bf3,
                                                             acc3[mt], 0, 0, 0);
      }
      // pre-BN layer3 -> scratch
#pragma unroll
      for (int mt = 0; mt < 8; mt++) {
        int ch0 = mt * 16 + q * 4;
        *(uint2*)&x3s[w][n][ch0] = make_uint2(packbf(acc3[mt][0], acc3[mt][1]),
                                              packbf(acc3[mt][2], acc3[mt][3]));
      }
    }
    asm volatile("s_waitcnt lgkmcnt(0)" ::: "memory");
    // readback reduce: this lane owns channels (2*lane, 2*lane+1)
    if (2 * lane < CLs) {
#pragma unroll
      for (int pos = 0; pos < 16; pos++) {
        uint32_t u = *(const uint32_t*)&x3s[w][pos][2 * lane];
        float v0 = __uint_as_float(u << 16);
        float v1v = __uint_as_float(u & 0xffff0000u);
        sS0 += v0;  sS20 = fmaf(v0, v0, sS20);
        sS1 += v1v; sS21 = fmaf(v1v, v1v, sS21);
        if (NL == 3) {
          mx0 = fmaxf(mx0, v0);  mn0 = fminf(mn0, v0);
          mx1 = fmaxf(mx1, v1v); mn1 = fminf(mn1, v1v);
        }
      }
    }
    if (NL == 3) {
      bool fl = (K == 64) ? (tl == 3) : ((tl & 1) == 1);
      if (fl) {
        int center = (K == 64) ? (blockIdx.x * 4 + w)
                               : (blockIdx.x * 8 + w * 2 + (tl >> 1));
        // bf16 store (lossless; verified R6)
        *(uint32_t*)&maxbuf[(size_t)center * 128 + 2 * lane] = packbf(mx0, mx1);
        *(uint32_t*)&minbuf[(size_t)center * 128 + 2 * lane] = packbf(mn0, mn1);
        mx0 = mx1 = -3.4e38f; mn0 = mn1 = 3.4e38f;
      }
    }
    asm volatile("s_waitcnt lgkmcnt(0)" ::: "memory");   // scratch reuse next tl
  }

  // ---- stats: per-wave LDS row, then one slotted flush per block ----
  {
    int ch = 2 * lane;
    if (ch < CLs) {
      sAccW[w][ch] = sS0;        sAccW[w][ch + 1] = sS1;
      sAccW[w][CLs + ch] = sS20; sAccW[w][CLs + ch + 1] = sS21;
    }
  }
  __syncthreads();
  float* dst = stats + (size_t)(blockIdx.x & (NSLOT - 1)) * (2 * CLs);
  for (int i = t; i < 2 * CLs; i += 256)
    atomicAdd(&dst[i], sAccW[0][i] + sAccW[1][i] + sAccW[2][i] + sAccW[3][i]);
}

// ---------------- final output: affine(max/min by sign) + relu, transposed write ----------------
// Both scales in one launch; reads the bf16 max/min buffers (expand via <<16).
// R10: BN3 coeffs computed inline from stats (bit-exact vs old finalize).
__global__ __launch_bounds__(256) void outwrite_fused(
    const ushort* __restrict__ mx0buf, const ushort* __restrict__ mn0buf,
    const ushort* __restrict__ mx1buf, const ushort* __restrict__ mn1buf,
    const float* __restrict__ st30, const float* __restrict__ g30,
    const float* __restrict__ be30, float invP0,
    const float* __restrict__ st31, const float* __restrict__ g31,
    const float* __restrict__ be31, float invP1,
    float* __restrict__ out_feat) {
  __shared__ float tile[64 * 130];
  __shared__ float cA3s[128], cC3s[128];
  int bx = blockIdx.x;
  const ushort* mxb; const ushort* mnb;
  const float* st; const float* g; const float* be; float invP;
  int chOff, c0;
  if (bx < BM / 64) {
    mxb = mx0buf; mnb = mn0buf; st = st30; g = g30; be = be30; invP = invP0;
    chOff = 0; c0 = bx * 64;
  } else {
    mxb = mx1buf; mnb = mn1buf; st = st31; g = g31; be = be31; invP = invP1;
    chOff = 128; c0 = (bx - BM / 64) * 64;
  }
  int t = threadIdx.x;
  if (t < 128) {
    float s = 0.f, s2 = 0.f;
    for (int sl = 0; sl < NSLOT; sl++) {
      s  += st[sl * 256 + t];
      s2 += st[sl * 256 + 128 + t];
    }
    float mu = s * invP;
    float var = fmaf(s2, invP, -(mu * mu));
    float a = g[t] / sqrtf(var + 1e-5f);
    cA3s[t] = a;
    cC3s[t] = fmaf(-a, mu, be[t]);
  }
  __syncthreads();
#pragma unroll
  for (int i = 0; i < 32; i++) {
    int e = i * 256 + t;
    int lc = e >> 7, o = e & 127;
    float a = cA3s[o];
    float mv = __uint_as_float(((uint32_t)mxb[(size_t)(c0 + lc) * 128 + o]) << 16);
    float nv = __uint_as_float(((uint32_t)mnb[(size_t)(c0 + lc) * 128 + o]) << 16);
    float v = (a >= 0.f) ? fmaf(a, mv, cC3s[o]) : fmaf(a, nv, cC3s[o]);
    tile[lc * 130 + o] = fmaxf(v, 0.f);
  }
  __syncthreads();
  int b = c0 >> 10, m0 = c0 & 1023;
#pragma unroll
  for (int j = 0; j < 32; j++) {
    int e = j * 256 + t;
    int lm = e & 63, o = e >> 6;
    out_feat[((size_t)(b * 256 + chOff + o)) * MCTR + m0 + lm] = tile[lm * 130 + o];
  }
}

// ======================= host launch =======================
extern "C" void kernel_launch(void* const* d_in, const int* in_sizes, int n_in,
                              void* d_out, int out_size, void* d_ws, size_t ws_size,
                              hipStream_t stream) {
  (void)in_sizes; (void)n_in; (void)out_size;
  const float* pc   = (const float*)d_in[0];
  const float* feat = (const float*)d_in[1];
  const float *Wp[2][3], *bp[2][3], *gp[2][3], *bep[2][3];
  for (int s = 0; s < 2; s++)
    for (int l = 0; l < 3; l++) {
      int base = 2 + (s * 3 + l) * 4;
      Wp[s][l]  = (const float*)d_in[base + 0];
      bp[s][l]  = (const float*)d_in[base + 1];
      gp[s][l]  = (const float*)d_in[base + 2];
      bep[s][l] = (const float*)d_in[base + 3];
    }

  char* ws = (char*)d_ws;
  float*  statsR  = (float*) (ws + 0x10000);     // 6 x NSLOT x 256 f32 = 192 KB
  float*  wt      = (float*) (ws + 0x42000);     // 8576 f32
  ushort* wf      = (ushort*)(ws + 0x50000);     // 60 KB bf16 A-frags
  ushort* Ub0     = (ushort*)(ws + 0x100000);    // 8 MB [b][n][64] bf16
  ushort* Ub1     = (ushort*)(ws + 0x900000);    // 8 MB
  int*    gidx0   = (int*)   (ws + 0x1100000);   // 2 MB
  int*    gidx1   = (int*)   (ws + 0x1300000);   // 4 MB
  ushort* mxb0    = (ushort*)(ws + 0x1700000);   // 4 MB bf16 [center][128]
  ushort* mnb0    = (ushort*)(ws + 0x1B00000);   // 4 MB
  ushort* mxb1    = (ushort*)(ws + 0x1F00000);   // 4 MB
  ushort* mnb1    = (ushort*)(ws + 0x2300000);   // 4 MB
  const unsigned long long WS_NEEDED = 0x2700000ULL;   // ~39.3 MB
  if (ws_size < WS_NEEDED) {
    fprintf(stderr, "[kernel] ws too small: %zu < %llu\n", ws_size, WS_NEEDED);
    return;
  }

  float* out_newpc = (float*)d_out;
  float* out_feat  = (float*)d_out + (size_t)BATCH * 3 * MCTR;

  const int P0 = BM * 32, P1 = BM * 64;
  const int LSTRIDE = NSLOT * 256;
  float* st10 = statsR + 0 * LSTRIDE, *st20 = statsR + 1 * LSTRIDE, *st30 = statsR + 2 * LSTRIDE;
  float* st11 = statsR + 3 * LSTRIDE, *st21 = statsR + 4 * LSTRIDE, *st31 = statsR + 5 * LSTRIDE;

  hipMemsetAsync(statsR, 0, 6 * NSLOT * 256 * sizeof(float), stream);
  // fused: FPS (blocks 0-15) || U0 (16-271) || U1 (272-527) || prep (528-681)
  fused_stageA<<<682, 256, 0, stream>>>(pc, feat,
                                        Wp[0][0], bp[0][0], Wp[0][1], Wp[0][2],
                                        Wp[1][0], bp[1][0], Wp[1][1], Wp[1][2],
                                        out_newpc, Ub0, Ub1, wt, wf);
  ballq_fused<<<BM / 2, 256, 0, stream>>>(pc, out_newpc, gidx0, gidx1,
                                          (float)(0.1 * 0.1), (float)(0.2 * 0.2));

  l1_fused<<<P0 / 128 + P1 / 128, 128, 0, stream>>>(Ub0, Ub1, pc, out_newpc,
                                                    gidx0, gidx1,
                                                    wt + 4096, wt + 8384, st10, st11);

  // BN1 coeffs computed inline from st10/st11 inside each consumer.
  mfma_pass<32, 64, 2><<<P0 / 256, 256, 0, stream>>>(Ub0, pc, out_newpc, gidx0,
      wt + 4096, wf + 0, wf + 4096, bp[0][1], bp[0][2],
      st10, gp[0][0], bep[0][0], nullptr, nullptr, nullptr, 1.0f / P0,
      st20, nullptr, nullptr);
  mfma_pass<64, 96, 2><<<P1 / 256, 256, 0, stream>>>(Ub1, pc, out_newpc, gidx1,
      wt + 8384, wf + 12288, wf + 18432, bp[1][1], bp[1][2],
      st11, gp[1][0], bep[1][0], nullptr, nullptr, nullptr, 1.0f / P1,
      st21, nullptr, nullptr);

  mfma_pass<32, 64, 3><<<P0 / 256, 256, 0, stream>>>(Ub0, pc, out_newpc, gidx0,
      wt + 4096, wf + 0, wf + 4096, bp[0][1], bp[0][2],
      st10, gp[0][0], bep[0][0], st20, gp[0][1], bep[0][1], 1.0f / P0,
      st30, mxb0, mnb0);
  mfma_pass<64, 96, 3><<<P1 / 256, 256, 0, stream>>>(Ub1, pc, out_newpc, gidx1,
      wt + 8384, wf + 12288, wf + 18432, bp[1][1], bp[1][2],
      st11, gp[1][0], bep[1][0], st21, gp[1][1], bep[1][1], 1.0f / P1,
      st31, mxb1, mnb1);

  // both output writes in one launch; BN3 coeffs inline from st30/st31
  outwrite_fused<<<2 * (BM / 64), 256, 0, stream>>>(mxb0, mnb0, mxb1, mnb1,
                                                    st30, gp[0][2], bep[0][2], 1.0f / P0,
                                                    st31, gp[1][2], bep[1][2], 1.0f / P1,
                                                    out_feat);
}